// Round 1
// baseline (4492.488 us; speedup 1.0000x reference)
//
#include <hip/hip_runtime.h>
#include <hip/hip_bf16.h>
#include <math.h>

// Problem constants
#define BB 4
#define NN 4096
#define EE 256
#define HH 1024
#define NW 12
#define NL 13
#define MM (BB * NN)   // 16384 rows

__device__ __forceinline__ float gelu_exact(float x) {
    return 0.5f * x * (1.0f + erff(x * 0.70710678118654752f));
}

// ---------------------------------------------------------------------------
// Tiled f32 GEMM: C[M,N] = op(A[M,K] @ B[K,N] + bias[N]), op = gelu or id
// BM=BN=64, BK=16, 256 threads, 4x4 per thread.
// ---------------------------------------------------------------------------
#define BM 64
#define BN 64
#define BK 16

__global__ __launch_bounds__(256) void gemm_f32(
    const float* __restrict__ A, const float* __restrict__ Bw,
    const float* __restrict__ bias, float* __restrict__ C,
    int M, int N, int K, int do_gelu)
{
    __shared__ float As[BK][BM + 1];
    __shared__ float Bs[BK][BN + 1];

    const int bx = blockIdx.x;   // N tile
    const int by = blockIdx.y;   // M tile
    const int tid = threadIdx.x; // 0..255
    const int tx = tid & 15;     // 0..15 -> N micro
    const int ty = tid >> 4;     // 0..15 -> M micro

    const int row0 = by * BM;
    const int col0 = bx * BN;

    float acc[4][4] = {};

    for (int k0 = 0; k0 < K; k0 += BK) {
        // A tile: 64x16
        #pragma unroll
        for (int i = tid; i < BM * BK; i += 256) {
            int m = i >> 4;       // /BK
            int k = i & (BK - 1);
            As[k][m] = A[(size_t)(row0 + m) * K + (k0 + k)];
        }
        // B tile: 16x64 (coalesced)
        #pragma unroll
        for (int i = tid; i < BK * BN; i += 256) {
            int k = i >> 6;       // /BN
            int n = i & (BN - 1);
            Bs[k][n] = Bw[(size_t)(k0 + k) * N + (col0 + n)];
        }
        __syncthreads();
        #pragma unroll
        for (int kk = 0; kk < BK; ++kk) {
            float a[4], b[4];
            #pragma unroll
            for (int i = 0; i < 4; ++i) a[i] = As[kk][ty * 4 + i];
            #pragma unroll
            for (int j = 0; j < 4; ++j) b[j] = Bs[kk][tx * 4 + j];
            #pragma unroll
            for (int i = 0; i < 4; ++i)
                #pragma unroll
                for (int j = 0; j < 4; ++j)
                    acc[i][j] += a[i] * b[j];
        }
        __syncthreads();
    }

    #pragma unroll
    for (int i = 0; i < 4; ++i) {
        const int m = row0 + ty * 4 + i;
        #pragma unroll
        for (int j = 0; j < 4; ++j) {
            const int n = col0 + tx * 4 + j;
            float v = acc[i][j] + bias[n];
            if (do_gelu) v = gelu_exact(v);
            C[(size_t)m * N + n] = v;
        }
    }
}

// ---------------------------------------------------------------------------
// Second layer of the link-weight MLP: W[r, m, l] = Wh[r,:] @ W2[:, l] + b2[l]
// One thread per (row, l). H=1024, NL=13.
// ---------------------------------------------------------------------------
__global__ __launch_bounds__(256) void w2_kernel(
    const float* __restrict__ Wh,   // MM x HH
    const float* __restrict__ W2,   // HH x NL
    const float* __restrict__ b2,   // NL
    float* __restrict__ Wout,       // MM x NW x NL
    int m)
{
    int idx = blockIdx.x * 256 + threadIdx.x;
    if (idx >= MM * NL) return;
    int r = idx / NL;
    int l = idx - r * NL;
    const float* wh = Wh + (size_t)r * HH;
    float acc = b2[l];
    for (int h = 0; h < HH; ++h)
        acc += wh[h] * W2[h * NL + l];
    Wout[((size_t)r * NW + m) * NL + l] = acc;
}

// ---------------------------------------------------------------------------
// One chord propagation step:
//   Vout[b,n,e] = Vin[b,n,e] + sum_l W[b,n,m,l] * Vin[b, cols[n,l], e]
// One block (256 threads) per row; e = threadIdx.x.
// ---------------------------------------------------------------------------
__global__ __launch_bounds__(256) void chord_step(
    const float* __restrict__ Vin,   // MM x EE
    const float* __restrict__ Wall,  // MM x NW x NL
    const int* __restrict__ cols,    // NN x NL
    float* __restrict__ Vout,        // MM x EE
    int m)
{
    const int r = blockIdx.x;        // 0..MM-1
    const int b = r >> 12;           // r / NN
    const int n = r & (NN - 1);
    const int e = threadIdx.x;

    const float* wrow = Wall + ((size_t)r * NW + m) * NL;
    const int* crow = cols + (size_t)n * NL;

    float acc = Vin[(size_t)r * EE + e];
    #pragma unroll
    for (int l = 0; l < NL; ++l) {
        const int cn = crow[l];
        acc += wrow[l] * Vin[((size_t)(b * NN + cn)) * EE + e];
    }
    Vout[(size_t)r * EE + e] = acc;
}

// ---------------------------------------------------------------------------
extern "C" void kernel_launch(void* const* d_in, const int* in_sizes, int n_in,
                              void* d_out, int out_size, void* d_ws, size_t ws_size,
                              hipStream_t stream)
{
    const float* V      = (const float*)d_in[0];
    const float* input  = (const float*)d_in[1];
    const float* g_W1   = (const float*)d_in[2];
    const float* g_b1   = (const float*)d_in[3];
    const float* g_W2   = (const float*)d_in[4];
    const float* g_b2   = (const float*)d_in[5];
    const float* f_W1   = (const float*)d_in[6];
    const float* f_b1   = (const float*)d_in[7];
    const float* f_W2   = (const float*)d_in[8];
    const float* f_b2   = (const float*)d_in[9];
    const int*   cols   = (const int*)d_in[10];
    float* out = (float*)d_out;

    char* ws = (char*)d_ws;
    float* Wh   = (float*)ws;                                  // MM*HH f32 = 64 MB
    float* Wall = (float*)(ws + (size_t)64 * 1024 * 1024);     // MM*NW*NL f32 ~ 9.75 MB
    float* Vbuf = (float*)(ws + (size_t)74 * 1024 * 1024);     // MM*EE f32 = 16 MB

    dim3 blk(256);
    dim3 gH(HH / BN, MM / BM);   // N=1024 tiles
    dim3 gE(EE / BN, MM / BM);   // N=256 tiles

    // 1. Y = gelu(V @ g_W1 + g_b1)            -> Wh
    gemm_f32<<<gH, blk, 0, stream>>>(V, g_W1, g_b1, Wh, MM, HH, EE, 1);
    // 2. V0 = Y @ g_W2 + g_b2                 -> out
    gemm_f32<<<gE, blk, 0, stream>>>(Wh, g_W2, g_b2, out, MM, EE, HH, 0);

    // 3. Link weights for all 12 levels (input is loop-invariant)
    for (int m = 0; m < NW; ++m) {
        gemm_f32<<<gH, blk, 0, stream>>>(input, f_W1 + (size_t)m * EE * HH,
                                         f_b1 + m * HH, Wh, MM, HH, EE, 1);
        w2_kernel<<<(MM * NL + 255) / 256, blk, 0, stream>>>(
            Wh, f_W2 + (size_t)m * HH * NL, f_b2 + m * NL, Wall, m);
    }

    // 4. 12 sequential chord steps, ping-pong out <-> Vbuf (12 even -> ends in out)
    const float* cur = out;
    float* nxt = Vbuf;
    for (int m = 0; m < NW; ++m) {
        chord_step<<<MM, blk, 0, stream>>>(cur, Wall, cols, nxt, m);
        float* t = (float*)cur;
        cur = nxt;
        nxt = t;
    }
}

// Round 2
// 729.075 us; speedup vs baseline: 6.1619x; 6.1619x over previous
//
#include <hip/hip_runtime.h>
#include <hip/hip_bf16.h>
#include <math.h>

// Problem constants
#define BB 4
#define NN 4096
#define EE 256
#define HH 1024
#define NW 12
#define NL 13
#define MM (BB * NN)   // 16384 rows

typedef __attribute__((ext_vector_type(8))) short short8;   // 8 bf16 (4 VGPRs)
typedef __attribute__((ext_vector_type(4))) float f32x4;

__device__ __forceinline__ float gelu_exact(float x) {
    return 0.5f * x * (1.0f + erff(x * 0.70710678118654752f));
}

__device__ __forceinline__ void load_lds16(const void* g, void* l) {
    __builtin_amdgcn_global_load_lds(
        (const __attribute__((address_space(1))) void*)g,
        (__attribute__((address_space(3))) void*)l, 16, 0, 0);
}

// ---------------------------------------------------------------------------
// bf16 MFMA GEMM (m97 structure): C[M,N] = op(A[M,K] @ Bt[N,K]^T + bias)
// 128x128 tile, BK=32, 256 threads (4 waves, 2x2), global_load_lds staging.
// ---------------------------------------------------------------------------
template<typename OutT, bool GELU>
__global__ __launch_bounds__(256) void gemm_bf16(
    const __hip_bfloat16* __restrict__ A,   // M x K  row-major
    const __hip_bfloat16* __restrict__ Bt,  // N x K  row-major (pre-transposed)
    const float* __restrict__ bias,         // N
    OutT* __restrict__ C,                   // M x N
    int M, int N, int K)
{
    __shared__ __hip_bfloat16 As[128 * 32];
    __shared__ __hip_bfloat16 Bs[128 * 32];

    const int tid = threadIdx.x;
    const int w = tid >> 6, l = tid & 63;
    const int wr = w >> 1, wc = w & 1;       // 2x2 wave grid, each 64x64
    const int row0 = blockIdx.y * 128;
    const int col0 = blockIdx.x * 128;

    // staging: tile = 128 rows x 32 bf16 = 8192 B = 512 x 16B chunks; 2 rounds
    const int c0 = w * 64 + l;               // round-0 chunk id
    const int c1 = c0 + 256;                 // round-1 chunk id
    const __hip_bfloat16* gA0 = A  + (size_t)(row0 + (c0 >> 2)) * K + (c0 & 3) * 8;
    const __hip_bfloat16* gA1 = A  + (size_t)(row0 + (c1 >> 2)) * K + (c1 & 3) * 8;
    const __hip_bfloat16* gB0 = Bt + (size_t)(col0 + (c0 >> 2)) * K + (c0 & 3) * 8;
    const __hip_bfloat16* gB1 = Bt + (size_t)(col0 + (c1 >> 2)) * K + (c1 & 3) * 8;
    char* dA0 = (char*)As + w * 1024;
    char* dA1 = (char*)As + w * 1024 + 4096;
    char* dB0 = (char*)Bs + w * 1024;
    char* dB1 = (char*)Bs + w * 1024 + 4096;

    const int lr = l & 15;                   // frag row (M or N index)
    const int lk = (l >> 4) * 8;             // frag k offset

    f32x4 acc[4][4] = {};

    for (int k0 = 0; k0 < K; k0 += 32) {
        load_lds16(gA0 + k0, dA0);
        load_lds16(gA1 + k0, dA1);
        load_lds16(gB0 + k0, dB0);
        load_lds16(gB1 + k0, dB1);
        __syncthreads();                     // drains vmcnt before barrier

        short8 a[4], b[4];
        #pragma unroll
        for (int m = 0; m < 4; ++m)
            a[m] = *(const short8*)&As[(wr * 64 + m * 16 + lr) * 32 + lk];
        #pragma unroll
        for (int n = 0; n < 4; ++n)
            b[n] = *(const short8*)&Bs[(wc * 64 + n * 16 + lr) * 32 + lk];
        #pragma unroll
        for (int m = 0; m < 4; ++m)
            #pragma unroll
            for (int n = 0; n < 4; ++n)
                acc[m][n] = __builtin_amdgcn_mfma_f32_16x16x32_bf16(a[m], b[n], acc[m][n], 0, 0, 0);
        __syncthreads();
    }

    // epilogue: C/D layout col=lane&15, row=(lane>>4)*4+j (verified m89/m91)
    #pragma unroll
    for (int m = 0; m < 4; ++m) {
        #pragma unroll
        for (int n = 0; n < 4; ++n) {
            const int col = col0 + wc * 64 + n * 16 + lr;
            const float bv = bias[col];
            #pragma unroll
            for (int j = 0; j < 4; ++j) {
                const int row = row0 + wr * 64 + m * 16 + (l >> 4) * 4 + j;
                float v = acc[m][n][j] + bv;
                if (GELU) v = gelu_exact(v);
                if constexpr (sizeof(OutT) == 2)
                    C[(size_t)row * N + col] = __float2bfloat16(v);
                else
                    C[(size_t)row * N + col] = v;
            }
        }
    }
}

// ---------------------------------------------------------------------------
// Second layer of link-weight MLP as LDS-free MFMA GEMM, N padded 13->16:
// Wall[r, m, l] = Wh[r,:] @ W2t[l,:] + b2[l].  One wave = 16 rows.
// ---------------------------------------------------------------------------
__global__ __launch_bounds__(256) void w2_mfma(
    const __hip_bfloat16* __restrict__ Wh,   // MM x HH
    const __hip_bfloat16* __restrict__ W2t,  // 16 x HH (level m, zero-padded)
    const float* __restrict__ b2,            // NL (level m)
    float* __restrict__ Wall,                // MM x NW x 16
    int m)
{
    const int w = threadIdx.x >> 6, l = threadIdx.x & 63;
    const int r0 = blockIdx.x * 64 + w * 16;
    const int lr = l & 15, lk = (l >> 4) * 8;

    const __hip_bfloat16* aP = Wh  + (size_t)(r0 + lr) * HH + lk;
    const __hip_bfloat16* bP = W2t + (size_t)lr * HH + lk;

    f32x4 acc = {};
    #pragma unroll 4
    for (int k = 0; k < HH; k += 32) {
        short8 a = *(const short8*)(aP + k);
        short8 b = *(const short8*)(bP + k);
        acc = __builtin_amdgcn_mfma_f32_16x16x32_bf16(a, b, acc, 0, 0, 0);
    }
    #pragma unroll
    for (int j = 0; j < 4; ++j) {
        const int row = r0 + (l >> 4) * 4 + j;
        const float v = acc[j] + (lr < NL ? b2[lr] : 0.f);
        Wall[((size_t)row * NW + m) * 16 + lr] = v;
    }
}

// ---------------------------------------------------------------------------
// Converters
// ---------------------------------------------------------------------------
struct bf4 { __hip_bfloat16 a, b, c, d; };

__global__ __launch_bounds__(256) void cvt_bf16(
    const float* __restrict__ in, __hip_bfloat16* __restrict__ out, int n4)
{
    int i = blockIdx.x * 256 + threadIdx.x;
    if (i >= n4) return;
    float4 v = ((const float4*)in)[i];
    bf4 o;
    o.a = __float2bfloat16(v.x); o.b = __float2bfloat16(v.y);
    o.c = __float2bfloat16(v.z); o.d = __float2bfloat16(v.w);
    ((bf4*)out)[i] = o;
}

// in: batch x K x N (f32, row-major) -> out: batch x N x K (bf16)
__global__ __launch_bounds__(256) void transpose_cvt(
    const float* __restrict__ in, __hip_bfloat16* __restrict__ out, int K, int N)
{
    __shared__ float t[32][33];
    const int bz = blockIdx.z;
    const float* inB = in + (size_t)bz * K * N;
    __hip_bfloat16* outB = out + (size_t)bz * K * N;
    const int n0 = blockIdx.x * 32, k0 = blockIdx.y * 32;
    const int tx = threadIdx.x & 31, ty = threadIdx.x >> 5;  // 32 x 8
    #pragma unroll
    for (int i = 0; i < 32; i += 8)
        t[ty + i][tx] = inB[(size_t)(k0 + ty + i) * N + n0 + tx];
    __syncthreads();
    #pragma unroll
    for (int i = 0; i < 32; i += 8)
        outB[(size_t)(n0 + ty + i) * K + k0 + tx] = __float2bfloat16(t[tx][ty + i]);
}

// f_W2 [NW][HH][NL] f32 -> W2t_all [NW][16][HH] bf16, rows 13..15 zero
__global__ __launch_bounds__(256) void w2t_cvt(
    const float* __restrict__ f_W2, __hip_bfloat16* __restrict__ W2t)
{
    int idx = blockIdx.x * 256 + threadIdx.x;
    if (idx >= NW * 16 * HH) return;
    const int m = idx >> 14;           // /(16*1024)
    const int n = (idx >> 10) & 15;
    const int h = idx & 1023;
    const float v = (n < NL) ? f_W2[((size_t)m * HH + h) * NL + n] : 0.f;
    W2t[idx] = __float2bfloat16(v);
}

// ---------------------------------------------------------------------------
// Chord step (f32, float4-vectorized): 4 rows per block, 64 lanes per row
// ---------------------------------------------------------------------------
__global__ __launch_bounds__(256) void chord_step(
    const float* __restrict__ Vin,   // MM x EE
    const float* __restrict__ Wall,  // MM x NW x 16
    const int* __restrict__ cols,    // NN x NL
    float* __restrict__ Vout,        // MM x EE
    int m)
{
    const int t = threadIdx.x;
    const int r = blockIdx.x * 4 + (t >> 6);
    const int e = t & 63;
    const int b = r >> 12;
    const int n = r & (NN - 1);

    const float* wrow = Wall + ((size_t)r * NW + m) * 16;
    const int* crow = cols + (size_t)n * NL;
    const float4* v4 = (const float4*)Vin;

    float4 acc = v4[(size_t)r * 64 + e];
    #pragma unroll
    for (int l = 0; l < NL; ++l) {
        const int cn = crow[l];
        const float wv = wrow[l];
        const float4 x = v4[((size_t)((b << 12) | cn)) * 64 + e];
        acc.x += wv * x.x; acc.y += wv * x.y;
        acc.z += wv * x.z; acc.w += wv * x.w;
    }
    ((float4*)Vout)[(size_t)r * 64 + e] = acc;
}

// ---------------------------------------------------------------------------
extern "C" void kernel_launch(void* const* d_in, const int* in_sizes, int n_in,
                              void* d_out, int out_size, void* d_ws, size_t ws_size,
                              hipStream_t stream)
{
    const float* V      = (const float*)d_in[0];
    const float* input  = (const float*)d_in[1];
    const float* g_W1   = (const float*)d_in[2];
    const float* g_b1   = (const float*)d_in[3];
    const float* g_W2   = (const float*)d_in[4];
    const float* g_b2   = (const float*)d_in[5];
    const float* f_W1   = (const float*)d_in[6];
    const float* f_b1   = (const float*)d_in[7];
    const float* f_W2   = (const float*)d_in[8];
    const float* f_b2   = (const float*)d_in[9];
    const int*   cols   = (const int*)d_in[10];
    float* out = (float*)d_out;

    char* ws = (char*)d_ws;
    size_t o = 0;
    __hip_bfloat16* Vb     = (__hip_bfloat16*)(ws + o); o += (size_t)MM * EE * 2;        // 8 MB
    __hip_bfloat16* Xb     = (__hip_bfloat16*)(ws + o); o += (size_t)MM * EE * 2;        // 8 MB
    __hip_bfloat16* gW1t   = (__hip_bfloat16*)(ws + o); o += (size_t)HH * EE * 2;        // 512 KB
    __hip_bfloat16* gW2t   = (__hip_bfloat16*)(ws + o); o += (size_t)EE * HH * 2;        // 512 KB
    __hip_bfloat16* fW1t   = (__hip_bfloat16*)(ws + o); o += (size_t)NW * HH * EE * 2;   // 6 MB
    __hip_bfloat16* W2tA   = (__hip_bfloat16*)(ws + o); o += (size_t)NW * 16 * HH * 2;   // 384 KB
    __hip_bfloat16* Whb    = (__hip_bfloat16*)(ws + o); o += (size_t)MM * HH * 2;        // 32 MB
    float*          Wall   = (float*)(ws + o);          o += (size_t)MM * NW * 16 * 4;   // 12 MB
    float*          Vbuf   = (float*)(ws + o);          o += (size_t)MM * EE * 4;        // 16 MB

    dim3 blk(256);

    // 0. dtype conversion / weight transposes
    cvt_bf16<<<(MM * EE / 4 + 255) / 256, blk, 0, stream>>>(V, Vb, MM * EE / 4);
    cvt_bf16<<<(MM * EE / 4 + 255) / 256, blk, 0, stream>>>(input, Xb, MM * EE / 4);
    transpose_cvt<<<dim3(HH / 32, EE / 32, 1),  blk, 0, stream>>>(g_W1, gW1t, EE, HH);
    transpose_cvt<<<dim3(EE / 32, HH / 32, 1),  blk, 0, stream>>>(g_W2, gW2t, HH, EE);
    transpose_cvt<<<dim3(HH / 32, EE / 32, NW), blk, 0, stream>>>(f_W1, fW1t, EE, HH);
    w2t_cvt<<<(NW * 16 * HH + 255) / 256, blk, 0, stream>>>(f_W2, W2tA);

    // 1-2. Gate MLP on V
    gemm_bf16<__hip_bfloat16, true><<<dim3(HH / 128, MM / 128), blk, 0, stream>>>(
        Vb, gW1t, g_b1, Whb, MM, HH, EE);
    gemm_bf16<float, false><<<dim3(EE / 128, MM / 128), blk, 0, stream>>>(
        Whb, gW2t, g_b2, out, MM, EE, HH);

    // 3. Link weights for all 12 levels (input is loop-invariant)
    for (int m = 0; m < NW; ++m) {
        gemm_bf16<__hip_bfloat16, true><<<dim3(HH / 128, MM / 128), blk, 0, stream>>>(
            Xb, fW1t + (size_t)m * HH * EE, f_b1 + m * HH, Whb, MM, HH, EE);
        w2_mfma<<<MM / 64, blk, 0, stream>>>(
            Whb, W2tA + (size_t)m * 16 * HH, f_b2 + m * NL, Wall, m);
    }

    // 4. 12 sequential chord steps, ping-pong out <-> Vbuf (even count -> ends in out)
    const float* cur = out;
    float* nxt = Vbuf;
    for (int m = 0; m < NW; ++m) {
        chord_step<<<MM / 4, blk, 0, stream>>>(cur, Wall, cols, nxt, m);
        float* tswap = (float*)cur;
        cur = nxt;
        nxt = tswap;
    }
}

// Round 3
// 496.326 us; speedup vs baseline: 9.0515x; 1.4689x over previous
//
#include <hip/hip_runtime.h>
#include <hip/hip_bf16.h>
#include <math.h>

// Problem constants
#define BB 4
#define NN 4096
#define EE 256
#define HH 1024
#define NW 12
#define NL 13
#define MM (BB * NN)   // 16384 rows

typedef __attribute__((ext_vector_type(8))) short short8;   // 8 bf16 (4 VGPRs)
typedef __attribute__((ext_vector_type(4))) float f32x4;

__device__ __forceinline__ float gelu_exact(float x) {
    return 0.5f * x * (1.0f + erff(x * 0.70710678118654752f));
}

__device__ __forceinline__ void load_lds16(const void* g, void* l) {
    __builtin_amdgcn_global_load_lds(
        (const __attribute__((address_space(1))) void*)g,
        (__attribute__((address_space(3))) void*)l, 16, 0, 0);
}

// ---------------------------------------------------------------------------
// bf16 MFMA GEMM (m97 structure): C[M,N] = op(A[M,K] @ Bt[N,K]^T + bias)
// 128x128 tile, BK=32, 256 threads (4 waves, 2x2). Used for the gate MLP.
// ---------------------------------------------------------------------------
template<typename OutT, bool GELU>
__global__ __launch_bounds__(256) void gemm_bf16(
    const __hip_bfloat16* __restrict__ A,   // M x K  row-major
    const __hip_bfloat16* __restrict__ Bt,  // N x K  row-major (pre-transposed)
    const float* __restrict__ bias,         // N
    OutT* __restrict__ C,                   // M x N
    int M, int N, int K)
{
    __shared__ __hip_bfloat16 As[128 * 32];
    __shared__ __hip_bfloat16 Bs[128 * 32];

    const int tid = threadIdx.x;
    const int w = tid >> 6, l = tid & 63;
    const int wr = w >> 1, wc = w & 1;       // 2x2 wave grid, each 64x64
    const int row0 = blockIdx.y * 128;
    const int col0 = blockIdx.x * 128;

    const int c0 = w * 64 + l;
    const int c1 = c0 + 256;
    const __hip_bfloat16* gA0 = A  + (size_t)(row0 + (c0 >> 2)) * K + (c0 & 3) * 8;
    const __hip_bfloat16* gA1 = A  + (size_t)(row0 + (c1 >> 2)) * K + (c1 & 3) * 8;
    const __hip_bfloat16* gB0 = Bt + (size_t)(col0 + (c0 >> 2)) * K + (c0 & 3) * 8;
    const __hip_bfloat16* gB1 = Bt + (size_t)(col0 + (c1 >> 2)) * K + (c1 & 3) * 8;
    char* dA0 = (char*)As + w * 1024;
    char* dA1 = (char*)As + w * 1024 + 4096;
    char* dB0 = (char*)Bs + w * 1024;
    char* dB1 = (char*)Bs + w * 1024 + 4096;

    const int lr = l & 15;
    const int lk = (l >> 4) * 8;

    f32x4 acc[4][4] = {};

    for (int k0 = 0; k0 < K; k0 += 32) {
        load_lds16(gA0 + k0, dA0);
        load_lds16(gA1 + k0, dA1);
        load_lds16(gB0 + k0, dB0);
        load_lds16(gB1 + k0, dB1);
        __syncthreads();

        short8 a[4], b[4];
        #pragma unroll
        for (int m = 0; m < 4; ++m)
            a[m] = *(const short8*)&As[(wr * 64 + m * 16 + lr) * 32 + lk];
        #pragma unroll
        for (int n = 0; n < 4; ++n)
            b[n] = *(const short8*)&Bs[(wc * 64 + n * 16 + lr) * 32 + lk];
        #pragma unroll
        for (int m = 0; m < 4; ++m)
            #pragma unroll
            for (int n = 0; n < 4; ++n)
                acc[m][n] = __builtin_amdgcn_mfma_f32_16x16x32_bf16(a[m], b[n], acc[m][n], 0, 0, 0);
        __syncthreads();
    }

    #pragma unroll
    for (int m = 0; m < 4; ++m) {
        #pragma unroll
        for (int n = 0; n < 4; ++n) {
            const int col = col0 + wc * 64 + n * 16 + lr;
            const float bv = bias[col];
            #pragma unroll
            for (int j = 0; j < 4; ++j) {
                const int row = row0 + wr * 64 + m * 16 + (l >> 4) * 4 + j;
                float v = acc[m][n][j] + bv;
                if (GELU) v = gelu_exact(v);
                if constexpr (sizeof(OutT) == 2)
                    C[(size_t)row * N + col] = __float2bfloat16(v);
                else
                    C[(size_t)row * N + col] = v;
            }
        }
    }
}

// ---------------------------------------------------------------------------
// Fused f-level kernel: for level m, rows [row0,row0+128):
//   Wall[r,m,l] = b2[l] + sum_h gelu(X@W1 + b1)[r,h] * W2[h,l]
// Loops over 8 H-col-tiles; gelu tile never leaves the block.
// Mini-GEMM: D[l, r] = sum_h W2T[l,h] * G[r,h]  (A=W2T, B=G, both b128 reads)
// G is XOR-swizzled in LDS to kill the 16-way conflict on 256B-stride reads.
// ---------------------------------------------------------------------------
__global__ __launch_bounds__(256) void f_fused(
    const __hip_bfloat16* __restrict__ X,     // MM x EE
    const __hip_bfloat16* __restrict__ W1t,   // NW x HH x EE (pre-transposed)
    const float* __restrict__ b1,             // NW x HH
    const __hip_bfloat16* __restrict__ W2t,   // NW x 16 x HH (padded, transposed)
    const float* __restrict__ b2,             // NW x NL
    float* __restrict__ Wall)                 // MM x NW x 16
{
    __shared__ __hip_bfloat16 As[128 * 32];
    __shared__ __hip_bfloat16 Bs[128 * 32];
    __shared__ __hip_bfloat16 G[128 * 128];   // gelu tile, swizzled

    const int tid = threadIdx.x;
    const int w = tid >> 6, l = tid & 63;
    const int wr = w >> 1, wc = w & 1;
    const int row0 = blockIdx.x * 128;
    const int m_lv = blockIdx.y;

    const __hip_bfloat16* Bt = W1t + (size_t)m_lv * HH * EE;
    const float* bias1 = b1 + m_lv * HH;

    const int c0 = w * 64 + l;
    const int c1 = c0 + 256;
    const __hip_bfloat16* gA0 = X + (size_t)(row0 + (c0 >> 2)) * EE + (c0 & 3) * 8;
    const __hip_bfloat16* gA1 = X + (size_t)(row0 + (c1 >> 2)) * EE + (c1 & 3) * 8;
    char* dA0 = (char*)As + w * 1024;
    char* dA1 = (char*)As + w * 1024 + 4096;
    char* dB0 = (char*)Bs + w * 1024;
    char* dB1 = (char*)Bs + w * 1024 + 4096;

    const int lr = l & 15;
    const int lk = (l >> 4) * 8;

    // W2T A-fragment base: row (l&15) of W2t[level], k-offset lk
    const __hip_bfloat16* w2p = W2t + ((size_t)m_lv * 16 + lr) * HH + lk;

    f32x4 wacc0 = {}, wacc1 = {};             // out[l, r] for rt=0,1 (rows w*32..)

    for (int ct = 0; ct < 8; ++ct) {
        const int col0 = ct * 128;
        const __hip_bfloat16* gB0 = Bt + (size_t)(col0 + (c0 >> 2)) * EE + (c0 & 3) * 8;
        const __hip_bfloat16* gB1 = Bt + (size_t)(col0 + (c1 >> 2)) * EE + (c1 & 3) * 8;

        f32x4 acc[4][4] = {};
        for (int k0 = 0; k0 < EE; k0 += 32) {
            load_lds16(gA0 + k0, dA0);
            load_lds16(gA1 + k0, dA1);
            load_lds16(gB0 + k0, dB0);
            load_lds16(gB1 + k0, dB1);
            __syncthreads();

            short8 a[4], b[4];
            #pragma unroll
            for (int mi = 0; mi < 4; ++mi)
                a[mi] = *(const short8*)&As[(wr * 64 + mi * 16 + lr) * 32 + lk];
            #pragma unroll
            for (int ni = 0; ni < 4; ++ni)
                b[ni] = *(const short8*)&Bs[(wc * 64 + ni * 16 + lr) * 32 + lk];
            #pragma unroll
            for (int mi = 0; mi < 4; ++mi)
                #pragma unroll
                for (int ni = 0; ni < 4; ++ni)
                    acc[mi][ni] = __builtin_amdgcn_mfma_f32_16x16x32_bf16(a[mi], b[ni], acc[mi][ni], 0, 0, 0);
            __syncthreads();
        }

        // gelu + bias -> bf16 -> swizzled LDS tile G[r][h] (this wave's 64x64 quadrant)
        #pragma unroll
        for (int ni = 0; ni < 4; ++ni) {
            const int h = wc * 64 + ni * 16 + lr;
            const float bv = bias1[col0 + h];
            #pragma unroll
            for (int mi = 0; mi < 4; ++mi) {
                #pragma unroll
                for (int j = 0; j < 4; ++j) {
                    const int r = wr * 64 + mi * 16 + (l >> 4) * 4 + j;
                    const float v = gelu_exact(acc[mi][ni][j] + bv);
                    const int byte = (r * 256 + h * 2) ^ ((r & 7) << 4);
                    *(__hip_bfloat16*)((char*)G + byte) = __float2bfloat16(v);
                }
            }
        }
        __syncthreads();

        // mini-GEMM: wave w covers rows [w*32, w*32+32), i.e. r-tiles 2w, 2w+1
        #pragma unroll
        for (int ks = 0; ks < 4; ++ks) {
            short8 aw = *(const short8*)(w2p + col0 + ks * 32);
            {   // rt = 0
                const int r = w * 32 + lr;
                const int byte = (r * 256 + (ks * 32 + lk) * 2) ^ ((r & 7) << 4);
                short8 bg = *(const short8*)((char*)G + byte);
                wacc0 = __builtin_amdgcn_mfma_f32_16x16x32_bf16(aw, bg, wacc0, 0, 0, 0);
            }
            {   // rt = 1
                const int r = w * 32 + 16 + lr;
                const int byte = (r * 256 + (ks * 32 + lk) * 2) ^ ((r & 7) << 4);
                short8 bg = *(const short8*)((char*)G + byte);
                wacc1 = __builtin_amdgcn_mfma_f32_16x16x32_bf16(aw, bg, wacc1, 0, 0, 0);
            }
        }
        __syncthreads();   // G reuse next ct (also separates As/Bs restage)
    }

    // write Wall: D layout col=lane&15 (=r-local), row=(lane>>4)*4+j (=l value)
    const float* b2m = b2 + m_lv * NL;
    #pragma unroll
    for (int j = 0; j < 4; ++j) {
        const int lval = (l >> 4) * 4 + j;
        const float bv = (lval < NL) ? b2m[lval] : 0.f;
        {
            const int r = row0 + w * 32 + lr;
            Wall[((size_t)r * NW + m_lv) * 16 + lval] = wacc0[j] + bv;
        }
        {
            const int r = row0 + w * 32 + 16 + lr;
            Wall[((size_t)r * NW + m_lv) * 16 + lval] = wacc1[j] + bv;
        }
    }
}

// ---------------------------------------------------------------------------
// Converters
// ---------------------------------------------------------------------------
struct bf4 { __hip_bfloat16 a, b, c, d; };

__global__ __launch_bounds__(256) void cvt_bf16(
    const float* __restrict__ in, __hip_bfloat16* __restrict__ out, int n4)
{
    int i = blockIdx.x * 256 + threadIdx.x;
    if (i >= n4) return;
    float4 v = ((const float4*)in)[i];
    bf4 o;
    o.a = __float2bfloat16(v.x); o.b = __float2bfloat16(v.y);
    o.c = __float2bfloat16(v.z); o.d = __float2bfloat16(v.w);
    ((bf4*)out)[i] = o;
}

// in: batch x K x N (f32, row-major) -> out: batch x N x K (bf16)
__global__ __launch_bounds__(256) void transpose_cvt(
    const float* __restrict__ in, __hip_bfloat16* __restrict__ out, int K, int N)
{
    __shared__ float t[32][33];
    const int bz = blockIdx.z;
    const float* inB = in + (size_t)bz * K * N;
    __hip_bfloat16* outB = out + (size_t)bz * K * N;
    const int n0 = blockIdx.x * 32, k0 = blockIdx.y * 32;
    const int tx = threadIdx.x & 31, ty = threadIdx.x >> 5;  // 32 x 8
    #pragma unroll
    for (int i = 0; i < 32; i += 8)
        t[ty + i][tx] = inB[(size_t)(k0 + ty + i) * N + n0 + tx];
    __syncthreads();
    #pragma unroll
    for (int i = 0; i < 32; i += 8)
        outB[(size_t)(n0 + ty + i) * K + k0 + tx] = __float2bfloat16(t[tx][ty + i]);
}

// f_W2 [NW][HH][NL] f32 -> W2t_all [NW][16][HH] bf16, rows 13..15 zero
__global__ __launch_bounds__(256) void w2t_cvt(
    const float* __restrict__ f_W2, __hip_bfloat16* __restrict__ W2t)
{
    int idx = blockIdx.x * 256 + threadIdx.x;
    if (idx >= NW * 16 * HH) return;
    const int m = idx >> 14;           // /(16*1024)
    const int n = (idx >> 10) & 15;
    const int h = idx & 1023;
    const float v = (n < NL) ? f_W2[((size_t)m * HH + h) * NL + n] : 0.f;
    W2t[idx] = __float2bfloat16(v);
}

// ---------------------------------------------------------------------------
// Chord step (f32, float4-vectorized): 4 rows per block, 64 lanes per row
// ---------------------------------------------------------------------------
__global__ __launch_bounds__(256) void chord_step(
    const float* __restrict__ Vin,   // MM x EE
    const float* __restrict__ Wall,  // MM x NW x 16
    const int* __restrict__ cols,    // NN x NL
    float* __restrict__ Vout,        // MM x EE
    int m)
{
    const int t = threadIdx.x;
    const int r = blockIdx.x * 4 + (t >> 6);
    const int e = t & 63;
    const int b = r >> 12;
    const int n = r & (NN - 1);

    const float* wrow = Wall + ((size_t)r * NW + m) * 16;
    const int* crow = cols + (size_t)n * NL;
    const float4* v4 = (const float4*)Vin;

    float4 acc = v4[(size_t)r * 64 + e];
    #pragma unroll
    for (int l = 0; l < NL; ++l) {
        const int cn = crow[l];
        const float wv = wrow[l];
        const float4 x = v4[((size_t)((b << 12) | cn)) * 64 + e];
        acc.x += wv * x.x; acc.y += wv * x.y;
        acc.z += wv * x.z; acc.w += wv * x.w;
    }
    ((float4*)Vout)[(size_t)r * 64 + e] = acc;
}

// ---------------------------------------------------------------------------
extern "C" void kernel_launch(void* const* d_in, const int* in_sizes, int n_in,
                              void* d_out, int out_size, void* d_ws, size_t ws_size,
                              hipStream_t stream)
{
    const float* V      = (const float*)d_in[0];
    const float* input  = (const float*)d_in[1];
    const float* g_W1   = (const float*)d_in[2];
    const float* g_b1   = (const float*)d_in[3];
    const float* g_W2   = (const float*)d_in[4];
    const float* g_b2   = (const float*)d_in[5];
    const float* f_W1   = (const float*)d_in[6];
    const float* f_b1   = (const float*)d_in[7];
    const float* f_W2   = (const float*)d_in[8];
    const float* f_b2   = (const float*)d_in[9];
    const int*   cols   = (const int*)d_in[10];
    float* out = (float*)d_out;

    char* ws = (char*)d_ws;
    size_t o = 0;
    __hip_bfloat16* Vb     = (__hip_bfloat16*)(ws + o); o += (size_t)MM * EE * 2;        // 8 MB
    __hip_bfloat16* Xb     = (__hip_bfloat16*)(ws + o); o += (size_t)MM * EE * 2;        // 8 MB
    __hip_bfloat16* gW1t   = (__hip_bfloat16*)(ws + o); o += (size_t)HH * EE * 2;        // 512 KB
    __hip_bfloat16* gW2t   = (__hip_bfloat16*)(ws + o); o += (size_t)EE * HH * 2;        // 512 KB
    __hip_bfloat16* fW1t   = (__hip_bfloat16*)(ws + o); o += (size_t)NW * HH * EE * 2;   // 6 MB
    __hip_bfloat16* W2tA   = (__hip_bfloat16*)(ws + o); o += (size_t)NW * 16 * HH * 2;   // 384 KB
    __hip_bfloat16* Whb    = (__hip_bfloat16*)(ws + o); o += (size_t)MM * HH * 2;        // 32 MB (gate only)
    float*          Wall   = (float*)(ws + o);          o += (size_t)MM * NW * 16 * 4;   // 12 MB
    float*          Vbuf   = (float*)(ws + o);          o += (size_t)MM * EE * 4;        // 16 MB

    dim3 blk(256);

    // 0. dtype conversion / weight transposes
    cvt_bf16<<<(MM * EE / 4 + 255) / 256, blk, 0, stream>>>(V, Vb, MM * EE / 4);
    cvt_bf16<<<(MM * EE / 4 + 255) / 256, blk, 0, stream>>>(input, Xb, MM * EE / 4);
    transpose_cvt<<<dim3(HH / 32, EE / 32, 1),  blk, 0, stream>>>(g_W1, gW1t, EE, HH);
    transpose_cvt<<<dim3(EE / 32, HH / 32, 1),  blk, 0, stream>>>(g_W2, gW2t, HH, EE);
    transpose_cvt<<<dim3(HH / 32, EE / 32, NW), blk, 0, stream>>>(f_W1, fW1t, EE, HH);
    w2t_cvt<<<(NW * 16 * HH + 255) / 256, blk, 0, stream>>>(f_W2, W2tA);

    // 1-2. Gate MLP on V
    gemm_bf16<__hip_bfloat16, true><<<dim3(HH / 128, MM / 128), blk, 0, stream>>>(
        Vb, gW1t, g_b1, Whb, MM, HH, EE);
    gemm_bf16<float, false><<<dim3(EE / 128, MM / 128), blk, 0, stream>>>(
        Whb, gW2t, g_b2, out, MM, EE, HH);

    // 3. All 12 levels' link weights in ONE fused launch (no Wh round-trip)
    f_fused<<<dim3(MM / 128, NW), blk, 0, stream>>>(Xb, fW1t, f_b1, W2tA, f_b2, Wall);

    // 4. 12 sequential chord steps, ping-pong out <-> Vbuf (even count -> ends in out)
    const float* cur = out;
    float* nxt = Vbuf;
    for (int m = 0; m < NW; ++m) {
        chord_step<<<MM / 4, blk, 0, stream>>>(cur, Wall, cols, nxt, m);
        float* tswap = (float*)cur;
        cur = nxt;
        nxt = tswap;
    }
}

// Round 4
// 472.942 us; speedup vs baseline: 9.4990x; 1.0494x over previous
//
#include <hip/hip_runtime.h>
#include <hip/hip_bf16.h>
#include <math.h>

// Problem constants
#define BB 4
#define NN 4096
#define EE 256
#define HH 1024
#define NW 12
#define NL 13
#define MM (BB * NN)   // 16384 rows

typedef __attribute__((ext_vector_type(8))) short short8;   // 8 bf16 (4 VGPRs)
typedef __attribute__((ext_vector_type(4))) float f32x4;

// Fast gelu: x * sigmoid(1.5957691*(x + 0.044715 x^3)) == tanh-approx gelu.
// Max |err| vs exact erf-gelu ~3e-4 -- far under the 5.6e-2 threshold.
__device__ __forceinline__ float gelu_fast(float x) {
    float x2 = x * x;
    float t  = __builtin_fmaf(0.044715f, x2, 1.0f);
    float e  = __expf(-1.5957691216057308f * (x * t));
    return x * __builtin_amdgcn_rcpf(1.0f + e);
}

__device__ __forceinline__ unsigned pack_bf16(float a, float b) {
    __hip_bfloat16 ha = __float2bfloat16(a);
    __hip_bfloat16 hb = __float2bfloat16(b);
    unsigned ua = *(const unsigned short*)&ha;
    unsigned ub = *(const unsigned short*)&hb;
    return ua | (ub << 16);
}

__device__ __forceinline__ void load_lds16(const void* g, void* l) {
    __builtin_amdgcn_global_load_lds(
        (const __attribute__((address_space(1))) void*)g,
        (__attribute__((address_space(3))) void*)l, 16, 0, 0);
}

// ---------------------------------------------------------------------------
// bf16 MFMA GEMM (m97 structure): C[M,N] = op(A[M,K] @ Bt[N,K]^T + bias)
// 128x128 tile, BK=32, 256 threads (4 waves, 2x2). Used for the gate MLP.
// ---------------------------------------------------------------------------
template<typename OutT, bool GELU>
__global__ __launch_bounds__(256) void gemm_bf16(
    const __hip_bfloat16* __restrict__ A,   // M x K  row-major
    const __hip_bfloat16* __restrict__ Bt,  // N x K  row-major (pre-transposed)
    const float* __restrict__ bias,         // N
    OutT* __restrict__ C,                   // M x N
    int M, int N, int K)
{
    __shared__ __hip_bfloat16 As[128 * 32];
    __shared__ __hip_bfloat16 Bs[128 * 32];

    const int tid = threadIdx.x;
    const int w = tid >> 6, l = tid & 63;
    const int wr = w >> 1, wc = w & 1;       // 2x2 wave grid, each 64x64
    const int row0 = blockIdx.y * 128;
    const int col0 = blockIdx.x * 128;

    const int c0 = w * 64 + l;
    const int c1 = c0 + 256;
    const __hip_bfloat16* gA0 = A  + (size_t)(row0 + (c0 >> 2)) * K + (c0 & 3) * 8;
    const __hip_bfloat16* gA1 = A  + (size_t)(row0 + (c1 >> 2)) * K + (c1 & 3) * 8;
    const __hip_bfloat16* gB0 = Bt + (size_t)(col0 + (c0 >> 2)) * K + (c0 & 3) * 8;
    const __hip_bfloat16* gB1 = Bt + (size_t)(col0 + (c1 >> 2)) * K + (c1 & 3) * 8;
    char* dA0 = (char*)As + w * 1024;
    char* dA1 = (char*)As + w * 1024 + 4096;
    char* dB0 = (char*)Bs + w * 1024;
    char* dB1 = (char*)Bs + w * 1024 + 4096;

    const int lr = l & 15;
    const int lk = (l >> 4) * 8;

    f32x4 acc[4][4] = {};

    for (int k0 = 0; k0 < K; k0 += 32) {
        load_lds16(gA0 + k0, dA0);
        load_lds16(gA1 + k0, dA1);
        load_lds16(gB0 + k0, dB0);
        load_lds16(gB1 + k0, dB1);
        __syncthreads();

        short8 a[4], b[4];
        #pragma unroll
        for (int m = 0; m < 4; ++m)
            a[m] = *(const short8*)&As[(wr * 64 + m * 16 + lr) * 32 + lk];
        #pragma unroll
        for (int n = 0; n < 4; ++n)
            b[n] = *(const short8*)&Bs[(wc * 64 + n * 16 + lr) * 32 + lk];
        #pragma unroll
        for (int m = 0; m < 4; ++m)
            #pragma unroll
            for (int n = 0; n < 4; ++n)
                acc[m][n] = __builtin_amdgcn_mfma_f32_16x16x32_bf16(a[m], b[n], acc[m][n], 0, 0, 0);
        __syncthreads();
    }

    #pragma unroll
    for (int m = 0; m < 4; ++m) {
        #pragma unroll
        for (int n = 0; n < 4; ++n) {
            const int col = col0 + wc * 64 + n * 16 + lr;
            const float bv = bias[col];
            #pragma unroll
            for (int j = 0; j < 4; ++j) {
                const int row = row0 + wr * 64 + m * 16 + (l >> 4) * 4 + j;
                float v = acc[m][n][j] + bv;
                if (GELU) v = gelu_fast(v);
                if constexpr (sizeof(OutT) == 2)
                    C[(size_t)row * N + col] = __float2bfloat16(v);
                else
                    C[(size_t)row * N + col] = v;
            }
        }
    }
}

// ---------------------------------------------------------------------------
// Fused f-level kernel, swapped-operand layout.
// First GEMM computes D[h][r] = mfma(a=W1t rows h, b=X rows r):
//   lane&15 = r (col), regs (lane>>4)*4+j = h (row)  ->  each lane holds 4
//   consecutive h for one r == exactly the mini-GEMM B-frag k layout.
// Wave w owns r-rows [w*32, w*32+32) end-to-end: G is wave-private (no
// barriers around the G phase), written as ds_write_b64, XOR-swizzled so
// both write (4/bank) and read (8/bank) hit the bank-minimum = conflict-free.
// ---------------------------------------------------------------------------
__global__ __launch_bounds__(256) void f_fused(
    const __hip_bfloat16* __restrict__ X,     // MM x EE
    const __hip_bfloat16* __restrict__ W1t,   // NW x HH x EE (pre-transposed)
    const float* __restrict__ b1,             // NW x HH
    const __hip_bfloat16* __restrict__ W2t,   // NW x 16 x HH (padded, transposed)
    const float* __restrict__ b2,             // NW x NL
    float* __restrict__ Wall)                 // MM x NW x 16
{
    __shared__ __hip_bfloat16 As[128 * 32];           // X tile   (8 KB)
    __shared__ __hip_bfloat16 Bs[128 * 32];           // W1 tile  (8 KB)
    __shared__ __align__(16) char Gb[4][4096];        // per-wave G half [32r][64h] (16 KB)
    __shared__ float biasS[HH];                       // 4 KB

    const int tid = threadIdx.x;
    const int w = tid >> 6, l = tid & 63;
    const int row0 = blockIdx.x * 128;
    const int m_lv = blockIdx.y;

    const __hip_bfloat16* Bt = W1t + (size_t)m_lv * HH * EE;

    // stage bias1 to LDS (256 threads x float4 = 1024 f32)
    ((float4*)biasS)[tid] = ((const float4*)(b1 + (size_t)m_lv * HH))[tid];

    const int c0 = w * 64 + l;
    const int c1 = c0 + 256;
    const __hip_bfloat16* gA0 = X + (size_t)(row0 + (c0 >> 2)) * EE + (c0 & 3) * 8;
    const __hip_bfloat16* gA1 = X + (size_t)(row0 + (c1 >> 2)) * EE + (c1 & 3) * 8;
    char* dA0 = (char*)As + w * 1024;
    char* dA1 = (char*)As + w * 1024 + 4096;
    char* dB0 = (char*)Bs + w * 1024;
    char* dB1 = (char*)Bs + w * 1024 + 4096;

    const int lr = l & 15;
    const int g  = l >> 4;
    const int lk = g * 8;

    const __hip_bfloat16* w2p = W2t + ((size_t)m_lv * 16 + lr) * HH + lk;
    char* Gw = Gb[w];

    f32x4 wacc0 = {}, wacc1 = {};

    for (int ct = 0; ct < 8; ++ct) {
        const int col0 = ct * 128;
        const __hip_bfloat16* gB0 = Bt + (size_t)(col0 + (c0 >> 2)) * EE + (c0 & 3) * 8;
        const __hip_bfloat16* gB1 = Bt + (size_t)(col0 + (c1 >> 2)) * EE + (c1 & 3) * 8;

        f32x4 acc[8][2] = {};   // [ni: h-tile][mi: r-tile]
        for (int k0 = 0; k0 < EE; k0 += 32) {
            load_lds16(gA0 + k0, dA0);
            load_lds16(gA1 + k0, dA1);
            load_lds16(gB0 + k0, dB0);
            load_lds16(gB1 + k0, dB1);
            __syncthreads();

            short8 a[8], b[2];
            #pragma unroll
            for (int ni = 0; ni < 8; ++ni)
                a[ni] = *(const short8*)&Bs[(ni * 16 + lr) * 32 + lk];
            #pragma unroll
            for (int mi = 0; mi < 2; ++mi)
                b[mi] = *(const short8*)&As[(w * 32 + mi * 16 + lr) * 32 + lk];
            #pragma unroll
            for (int ni = 0; ni < 8; ++ni)
                #pragma unroll
                for (int mi = 0; mi < 2; ++mi)
                    acc[ni][mi] = __builtin_amdgcn_mfma_f32_16x16x32_bf16(a[ni], b[mi], acc[ni][mi], 0, 0, 0);
            __syncthreads();
        }

        // Two 64-h halves: gelu+pack -> wave-private G half -> mini-GEMM.
        #pragma unroll
        for (int half = 0; half < 2; ++half) {
            #pragma unroll
            for (int ni4 = 0; ni4 < 4; ++ni4) {
                const int ni = half * 4 + ni4;
                const float4 bv = *(const float4*)&biasS[col0 + ni * 16 + g * 4];
                #pragma unroll
                for (int mi = 0; mi < 2; ++mi) {
                    const int rloc = mi * 16 + lr;
                    const float v0 = gelu_fast(acc[ni][mi][0] + bv.x);
                    const float v1 = gelu_fast(acc[ni][mi][1] + bv.y);
                    const float v2 = gelu_fast(acc[ni][mi][2] + bv.z);
                    const float v3 = gelu_fast(acc[ni][mi][3] + bv.w);
                    uint2 pk;
                    pk.x = pack_bf16(v0, v1);
                    pk.y = pack_bf16(v2, v3);
                    const int byte = (rloc * 128 + (ni4 * 16 + g * 4) * 2) ^ ((rloc & 7) << 4);
                    *(uint2*)(Gw + byte) = pk;
                }
            }
            #pragma unroll
            for (int ks2 = 0; ks2 < 2; ++ks2) {
                const int ks = half * 2 + ks2;
                const short8 aw = *(const short8*)(w2p + col0 + ks * 32);
                {
                    const int rloc = lr;
                    const int byte = (rloc * 128 + (ks2 * 32 + lk) * 2) ^ ((rloc & 7) << 4);
                    const short8 bg = *(const short8*)(Gw + byte);
                    wacc0 = __builtin_amdgcn_mfma_f32_16x16x32_bf16(aw, bg, wacc0, 0, 0, 0);
                }
                {
                    const int rloc = 16 + lr;
                    const int byte = (rloc * 128 + (ks2 * 32 + lk) * 2) ^ ((rloc & 7) << 4);
                    const short8 bg = *(const short8*)(Gw + byte);
                    wacc1 = __builtin_amdgcn_mfma_f32_16x16x32_bf16(aw, bg, wacc1, 0, 0, 0);
                }
            }
        }
    }

    // write Wall: D col = lane&15 (= r-local), row = (lane>>4)*4+j (= link l)
    const float* b2m = b2 + m_lv * NL;
    #pragma unroll
    for (int j = 0; j < 4; ++j) {
        const int lval = g * 4 + j;
        const float bv = (lval < NL) ? b2m[lval] : 0.f;
        {
            const int r = row0 + w * 32 + lr;
            Wall[((size_t)r * NW + m_lv) * 16 + lval] = wacc0[j] + bv;
        }
        {
            const int r = row0 + w * 32 + 16 + lr;
            Wall[((size_t)r * NW + m_lv) * 16 + lval] = wacc1[j] + bv;
        }
    }
}

// ---------------------------------------------------------------------------
// Converters
// ---------------------------------------------------------------------------
struct bf4 { __hip_bfloat16 a, b, c, d; };

__global__ __launch_bounds__(256) void cvt_bf16(
    const float* __restrict__ in, __hip_bfloat16* __restrict__ out, int n4)
{
    int i = blockIdx.x * 256 + threadIdx.x;
    if (i >= n4) return;
    float4 v = ((const float4*)in)[i];
    bf4 o;
    o.a = __float2bfloat16(v.x); o.b = __float2bfloat16(v.y);
    o.c = __float2bfloat16(v.z); o.d = __float2bfloat16(v.w);
    ((bf4*)out)[i] = o;
}

// in: batch x K x N (f32, row-major) -> out: batch x N x K (bf16)
__global__ __launch_bounds__(256) void transpose_cvt(
    const float* __restrict__ in, __hip_bfloat16* __restrict__ out, int K, int N)
{
    __shared__ float t[32][33];
    const int bz = blockIdx.z;
    const float* inB = in + (size_t)bz * K * N;
    __hip_bfloat16* outB = out + (size_t)bz * K * N;
    const int n0 = blockIdx.x * 32, k0 = blockIdx.y * 32;
    const int tx = threadIdx.x & 31, ty = threadIdx.x >> 5;  // 32 x 8
    #pragma unroll
    for (int i = 0; i < 32; i += 8)
        t[ty + i][tx] = inB[(size_t)(k0 + ty + i) * N + n0 + tx];
    __syncthreads();
    #pragma unroll
    for (int i = 0; i < 32; i += 8)
        outB[(size_t)(n0 + ty + i) * K + k0 + tx] = __float2bfloat16(t[tx][ty + i]);
}

// f_W2 [NW][HH][NL] f32 -> W2t_all [NW][16][HH] bf16, rows 13..15 zero
__global__ __launch_bounds__(256) void w2t_cvt(
    const float* __restrict__ f_W2, __hip_bfloat16* __restrict__ W2t)
{
    int idx = blockIdx.x * 256 + threadIdx.x;
    if (idx >= NW * 16 * HH) return;
    const int m = idx >> 14;           // /(16*1024)
    const int n = (idx >> 10) & 15;
    const int h = idx & 1023;
    const float v = (n < NL) ? f_W2[((size_t)m * HH + h) * NL + n] : 0.f;
    W2t[idx] = __float2bfloat16(v);
}

// ---------------------------------------------------------------------------
// Chord step (f32, float4-vectorized): 4 rows per block, 64 lanes per row
// ---------------------------------------------------------------------------
__global__ __launch_bounds__(256) void chord_step(
    const float* __restrict__ Vin,   // MM x EE
    const float* __restrict__ Wall,  // MM x NW x 16
    const int* __restrict__ cols,    // NN x NL
    float* __restrict__ Vout,        // MM x EE
    int m)
{
    const int t = threadIdx.x;
    const int r = blockIdx.x * 4 + (t >> 6);
    const int e = t & 63;
    const int b = r >> 12;
    const int n = r & (NN - 1);

    const float* wrow = Wall + ((size_t)r * NW + m) * 16;
    const int* crow = cols + (size_t)n * NL;
    const float4* v4 = (const float4*)Vin;

    float4 acc = v4[(size_t)r * 64 + e];
    #pragma unroll
    for (int l = 0; l < NL; ++l) {
        const int cn = crow[l];
        const float wv = wrow[l];
        const float4 x = v4[((size_t)((b << 12) | cn)) * 64 + e];
        acc.x += wv * x.x; acc.y += wv * x.y;
        acc.z += wv * x.z; acc.w += wv * x.w;
    }
    ((float4*)Vout)[(size_t)r * 64 + e] = acc;
}

// ---------------------------------------------------------------------------
extern "C" void kernel_launch(void* const* d_in, const int* in_sizes, int n_in,
                              void* d_out, int out_size, void* d_ws, size_t ws_size,
                              hipStream_t stream)
{
    const float* V      = (const float*)d_in[0];
    const float* input  = (const float*)d_in[1];
    const float* g_W1   = (const float*)d_in[2];
    const float* g_b1   = (const float*)d_in[3];
    const float* g_W2   = (const float*)d_in[4];
    const float* g_b2   = (const float*)d_in[5];
    const float* f_W1   = (const float*)d_in[6];
    const float* f_b1   = (const float*)d_in[7];
    const float* f_W2   = (const float*)d_in[8];
    const float* f_b2   = (const float*)d_in[9];
    const int*   cols   = (const int*)d_in[10];
    float* out = (float*)d_out;

    char* ws = (char*)d_ws;
    size_t o = 0;
    __hip_bfloat16* Vb     = (__hip_bfloat16*)(ws + o); o += (size_t)MM * EE * 2;        // 8 MB
    __hip_bfloat16* Xb     = (__hip_bfloat16*)(ws + o); o += (size_t)MM * EE * 2;        // 8 MB
    __hip_bfloat16* gW1t   = (__hip_bfloat16*)(ws + o); o += (size_t)HH * EE * 2;        // 512 KB
    __hip_bfloat16* gW2t   = (__hip_bfloat16*)(ws + o); o += (size_t)EE * HH * 2;        // 512 KB
    __hip_bfloat16* fW1t   = (__hip_bfloat16*)(ws + o); o += (size_t)NW * HH * EE * 2;   // 6 MB
    __hip_bfloat16* W2tA   = (__hip_bfloat16*)(ws + o); o += (size_t)NW * 16 * HH * 2;   // 384 KB
    __hip_bfloat16* Whb    = (__hip_bfloat16*)(ws + o); o += (size_t)MM * HH * 2;        // 32 MB (gate only)
    float*          Wall   = (float*)(ws + o);          o += (size_t)MM * NW * 16 * 4;   // 12 MB
    float*          Vbuf   = (float*)(ws + o);          o += (size_t)MM * EE * 4;        // 16 MB

    dim3 blk(256);

    // 0. dtype conversion / weight transposes
    cvt_bf16<<<(MM * EE / 4 + 255) / 256, blk, 0, stream>>>(V, Vb, MM * EE / 4);
    cvt_bf16<<<(MM * EE / 4 + 255) / 256, blk, 0, stream>>>(input, Xb, MM * EE / 4);
    transpose_cvt<<<dim3(HH / 32, EE / 32, 1),  blk, 0, stream>>>(g_W1, gW1t, EE, HH);
    transpose_cvt<<<dim3(EE / 32, HH / 32, 1),  blk, 0, stream>>>(g_W2, gW2t, HH, EE);
    transpose_cvt<<<dim3(HH / 32, EE / 32, NW), blk, 0, stream>>>(f_W1, fW1t, EE, HH);
    w2t_cvt<<<(NW * 16 * HH + 255) / 256, blk, 0, stream>>>(f_W2, W2tA);

    // 1-2. Gate MLP on V
    gemm_bf16<__hip_bfloat16, true><<<dim3(HH / 128, MM / 128), blk, 0, stream>>>(
        Vb, gW1t, g_b1, Whb, MM, HH, EE);
    gemm_bf16<float, false><<<dim3(EE / 128, MM / 128), blk, 0, stream>>>(
        Whb, gW2t, g_b2, out, MM, EE, HH);

    // 3. All 12 levels' link weights in ONE fused launch (no Wh round-trip)
    f_fused<<<dim3(MM / 128, NW), blk, 0, stream>>>(Xb, fW1t, f_b1, W2tA, f_b2, Wall);

    // 4. 12 sequential chord steps, ping-pong out <-> Vbuf (even count -> ends in out)
    const float* cur = out;
    float* nxt = Vbuf;
    for (int m = 0; m < NW; ++m) {
        chord_step<<<MM / 4, blk, 0, stream>>>(cur, Wall, cols, nxt, m);
        float* tswap = (float*)cur;
        cur = nxt;
        nxt = tswap;
    }
}

// Round 5
// 405.273 us; speedup vs baseline: 11.0851x; 1.1670x over previous
//
#include <hip/hip_runtime.h>
#include <hip/hip_bf16.h>
#include <math.h>

// Problem constants
#define BB 4
#define NN 4096
#define EE 256
#define HH 1024
#define NW 12
#define NL 13
#define MM (BB * NN)   // 16384 rows

typedef __attribute__((ext_vector_type(8))) short short8;   // 8 bf16 (4 VGPRs)
typedef __attribute__((ext_vector_type(4))) float f32x4;

// Fast gelu: x * sigmoid(1.5957691*(x + 0.044715 x^3)) == tanh-approx gelu.
__device__ __forceinline__ float gelu_fast(float x) {
    float x2 = x * x;
    float t  = __builtin_fmaf(0.044715f, x2, 1.0f);
    float e  = __expf(-1.5957691216057308f * (x * t));
    return x * __builtin_amdgcn_rcpf(1.0f + e);
}

__device__ __forceinline__ unsigned pack_bf16(float a, float b) {
    __hip_bfloat16 ha = __float2bfloat16(a);
    __hip_bfloat16 hb = __float2bfloat16(b);
    unsigned ua = *(const unsigned short*)&ha;
    unsigned ub = *(const unsigned short*)&hb;
    return ua | (ub << 16);
}

__device__ __forceinline__ void load_lds16(const void* g, void* l) {
    __builtin_amdgcn_global_load_lds(
        (const __attribute__((address_space(1))) void*)g,
        (__attribute__((address_space(3))) void*)l, 16, 0, 0);
}

// ---------------------------------------------------------------------------
// bf16 MFMA GEMM (m97 structure): C[M,N] = op(A[M,K] @ Bt[N,K]^T + bias)
// 128x128 tile, BK=32, 256 threads (4 waves, 2x2). Used for the gate MLP.
// ---------------------------------------------------------------------------
template<typename OutT, bool GELU>
__global__ __launch_bounds__(256) void gemm_bf16(
    const __hip_bfloat16* __restrict__ A,   // M x K  row-major
    const __hip_bfloat16* __restrict__ Bt,  // N x K  row-major (pre-transposed)
    const float* __restrict__ bias,         // N
    OutT* __restrict__ C,                   // M x N
    int M, int N, int K)
{
    __shared__ __hip_bfloat16 As[128 * 32];
    __shared__ __hip_bfloat16 Bs[128 * 32];

    const int tid = threadIdx.x;
    const int w = tid >> 6, l = tid & 63;
    const int wr = w >> 1, wc = w & 1;       // 2x2 wave grid, each 64x64
    const int row0 = blockIdx.y * 128;
    const int col0 = blockIdx.x * 128;

    const int c0 = w * 64 + l;
    const int c1 = c0 + 256;
    const __hip_bfloat16* gA0 = A  + (size_t)(row0 + (c0 >> 2)) * K + (c0 & 3) * 8;
    const __hip_bfloat16* gA1 = A  + (size_t)(row0 + (c1 >> 2)) * K + (c1 & 3) * 8;
    const __hip_bfloat16* gB0 = Bt + (size_t)(col0 + (c0 >> 2)) * K + (c0 & 3) * 8;
    const __hip_bfloat16* gB1 = Bt + (size_t)(col0 + (c1 >> 2)) * K + (c1 & 3) * 8;
    char* dA0 = (char*)As + w * 1024;
    char* dA1 = (char*)As + w * 1024 + 4096;
    char* dB0 = (char*)Bs + w * 1024;
    char* dB1 = (char*)Bs + w * 1024 + 4096;

    const int lr = l & 15;
    const int lk = (l >> 4) * 8;

    f32x4 acc[4][4] = {};

    for (int k0 = 0; k0 < K; k0 += 32) {
        load_lds16(gA0 + k0, dA0);
        load_lds16(gA1 + k0, dA1);
        load_lds16(gB0 + k0, dB0);
        load_lds16(gB1 + k0, dB1);
        __syncthreads();

        short8 a[4], b[4];
        #pragma unroll
        for (int m = 0; m < 4; ++m)
            a[m] = *(const short8*)&As[(wr * 64 + m * 16 + lr) * 32 + lk];
        #pragma unroll
        for (int n = 0; n < 4; ++n)
            b[n] = *(const short8*)&Bs[(wc * 64 + n * 16 + lr) * 32 + lk];
        #pragma unroll
        for (int m = 0; m < 4; ++m)
            #pragma unroll
            for (int n = 0; n < 4; ++n)
                acc[m][n] = __builtin_amdgcn_mfma_f32_16x16x32_bf16(a[m], b[n], acc[m][n], 0, 0, 0);
        __syncthreads();
    }

    #pragma unroll
    for (int m = 0; m < 4; ++m) {
        #pragma unroll
        for (int n = 0; n < 4; ++n) {
            const int col = col0 + wc * 64 + n * 16 + lr;
            const float bv = bias[col];
            #pragma unroll
            for (int j = 0; j < 4; ++j) {
                const int row = row0 + wr * 64 + m * 16 + (l >> 4) * 4 + j;
                float v = acc[m][n][j] + bv;
                if (GELU) v = gelu_fast(v);
                if constexpr (sizeof(OutT) == 2)
                    C[(size_t)row * N + col] = __float2bfloat16(v);
                else
                    C[(size_t)row * N + col] = v;
            }
        }
    }
}

// ---------------------------------------------------------------------------
// Fused f-level kernel v3.
//  - X fragments live in registers (loaded once per block): no A staging.
//  - ct loop: 16 tiles of 64 h-rows; per ct the FULL K=256 W1 sub-tile is
//    staged once into LDS layout Bs[kk][row][g] (kk = 32-elem k-slice) so
//    every ds_read_b128 is base + immediate offset at the 8/bank minimum.
//  - T14 split: ct+1's global_load_lds issue right after the k-loop sync;
//    gelu+pack+mini-GEMM run under the load flight; then one drain sync.
//  - Wave-private swizzled G half-tile: no barriers in the G/mini phase.
// ---------------------------------------------------------------------------
__global__ __launch_bounds__(256, 3) void f_fused(
    const __hip_bfloat16* __restrict__ X,     // MM x EE
    const __hip_bfloat16* __restrict__ W1t,   // NW x HH x EE (pre-transposed)
    const float* __restrict__ b1,             // NW x HH
    const __hip_bfloat16* __restrict__ W2t,   // NW x 16 x HH (padded, transposed)
    const float* __restrict__ b2,             // NW x NL
    float* __restrict__ Wall)                 // MM x NW x 16
{
    __shared__ __hip_bfloat16 Bs[8 * 64 * 32];        // 32 KB: [kk][row][32 elems]
    __shared__ __align__(16) char Gb[4][4096];        // per-wave G [32 r][64 h] (16 KB)
    __shared__ float biasS[HH];                       // 4 KB

    const int tid = threadIdx.x;
    const int w = tid >> 6, l = tid & 63;
    const int row0 = blockIdx.x * 128;
    const int m_lv = blockIdx.y;
    const int lr = l & 15;
    const int g  = l >> 4;
    const int lk = g * 8;

    const __hip_bfloat16* W1m = W1t + (size_t)m_lv * HH * EE;

    // stage bias1 to LDS (256 threads x float4 = 1024 f32)
    ((float4*)biasS)[tid] = ((const float4*)(b1 + (size_t)m_lv * HH))[tid];

    // X fragments in registers: rows w*32 + {0,16} + lr, all 8 k-slices.
    short8 xf[2][8];
    {
        const __hip_bfloat16* xp0 = X + (size_t)(row0 + w * 32 + lr) * EE + lk;
        #pragma unroll
        for (int kk = 0; kk < 8; ++kk) {
            xf[0][kk] = *(const short8*)(xp0 + kk * 32);
            xf[1][kk] = *(const short8*)(xp0 + 16 * EE + kk * 32);
        }
    }

    const __hip_bfloat16* w2p = W2t + ((size_t)m_lv * 16 + lr) * HH + lk;
    char* Gw = Gb[w];

    // staging: chunk c (0..2047): kk = c>>8, row = (c>>2)&63, g = c&3
    // src = W1 row (ct*64 + row), elems [kk*32 + g*8 ..+7]; dst = Bs + c*16.
    f32x4 wacc0 = {}, wacc1 = {};

    // prologue: stage ct = 0
    #pragma unroll
    for (int rstep = 0; rstep < 8; ++rstep) {
        const int c = rstep * 256 + tid;
        load_lds16(W1m + (size_t)((c >> 2) & 63) * EE + (c >> 8) * 32 + (c & 3) * 8,
                   (char*)Bs + c * 16);
    }
    __syncthreads();

    #pragma unroll 1
    for (int ct = 0; ct < 16; ++ct) {
        // ---- k-loop: 8 slices x (4 ds_read + 8 MFMA), X from registers ----
        f32x4 acc[4][2] = {};
        #pragma unroll
        for (int kk = 0; kk < 8; ++kk) {
            short8 a[4];
            #pragma unroll
            for (int ni = 0; ni < 4; ++ni)
                a[ni] = *(const short8*)((const char*)Bs +
                         (kk * 4096 + ni * 1024 + lr * 64 + g * 16));
            #pragma unroll
            for (int ni = 0; ni < 4; ++ni) {
                acc[ni][0] = __builtin_amdgcn_mfma_f32_16x16x32_bf16(a[ni], xf[0][kk], acc[ni][0], 0, 0, 0);
                acc[ni][1] = __builtin_amdgcn_mfma_f32_16x16x32_bf16(a[ni], xf[1][kk], acc[ni][1], 0, 0, 0);
            }
        }
        __syncthreads();                       // all waves done reading Bs

        // ---- issue next ct's staging; its flight hides under gelu+mini ----
        if (ct < 15) {
            const __hip_bfloat16* W1n = W1m + (size_t)(ct + 1) * 64 * EE;
            #pragma unroll
            for (int rstep = 0; rstep < 8; ++rstep) {
                const int c = rstep * 256 + tid;
                load_lds16(W1n + (size_t)((c >> 2) & 63) * EE + (c >> 8) * 32 + (c & 3) * 8,
                           (char*)Bs + c * 16);
            }
        }

        // ---- gelu + bias -> bf16 pack -> wave-private swizzled G ----
        #pragma unroll
        for (int ni = 0; ni < 4; ++ni) {
            const float4 bv = *(const float4*)&biasS[ct * 64 + ni * 16 + g * 4];
            #pragma unroll
            for (int mi = 0; mi < 2; ++mi) {
                const int rloc = mi * 16 + lr;
                const float v0 = gelu_fast(acc[ni][mi][0] + bv.x);
                const float v1 = gelu_fast(acc[ni][mi][1] + bv.y);
                const float v2 = gelu_fast(acc[ni][mi][2] + bv.z);
                const float v3 = gelu_fast(acc[ni][mi][3] + bv.w);
                uint2 pk;
                pk.x = pack_bf16(v0, v1);
                pk.y = pack_bf16(v2, v3);
                const int byte = (rloc * 128 + (ni * 16 + g * 4) * 2) ^ ((rloc & 7) << 4);
                *(uint2*)(Gw + byte) = pk;
            }
        }

        // ---- mini-GEMM: Wall-frag += W2t[ct k-range] x G ----
        #pragma unroll
        for (int ks2 = 0; ks2 < 2; ++ks2) {
            const short8 aw = *(const short8*)(w2p + ct * 64 + ks2 * 32);
            {
                const int byte = (lr * 128 + (ks2 * 32 + lk) * 2) ^ ((lr & 7) << 4);
                const short8 bg = *(const short8*)(Gw + byte);
                wacc0 = __builtin_amdgcn_mfma_f32_16x16x32_bf16(aw, bg, wacc0, 0, 0, 0);
            }
            {
                const int rloc = 16 + lr;
                const int byte = (rloc * 128 + (ks2 * 32 + lk) * 2) ^ ((rloc & 7) << 4);
                const short8 bg = *(const short8*)(Gw + byte);
                wacc1 = __builtin_amdgcn_mfma_f32_16x16x32_bf16(aw, bg, wacc1, 0, 0, 0);
            }
        }
        __syncthreads();                       // drain staging; Bs ready for ct+1
    }

    // write Wall: D col = lane&15 (= r-local), row = (lane>>4)*4+j (= link l)
    const float* b2m = b2 + m_lv * NL;
    #pragma unroll
    for (int j = 0; j < 4; ++j) {
        const int lval = g * 4 + j;
        const float bv = (lval < NL) ? b2m[lval] : 0.f;
        {
            const int r = row0 + w * 32 + lr;
            Wall[((size_t)r * NW + m_lv) * 16 + lval] = wacc0[j] + bv;
        }
        {
            const int r = row0 + w * 32 + 16 + lr;
            Wall[((size_t)r * NW + m_lv) * 16 + lval] = wacc1[j] + bv;
        }
    }
}

// ---------------------------------------------------------------------------
// Converters
// ---------------------------------------------------------------------------
struct bf4 { __hip_bfloat16 a, b, c, d; };

__global__ __launch_bounds__(256) void cvt_bf16(
    const float* __restrict__ in, __hip_bfloat16* __restrict__ out, int n4)
{
    int i = blockIdx.x * 256 + threadIdx.x;
    if (i >= n4) return;
    float4 v = ((const float4*)in)[i];
    bf4 o;
    o.a = __float2bfloat16(v.x); o.b = __float2bfloat16(v.y);
    o.c = __float2bfloat16(v.z); o.d = __float2bfloat16(v.w);
    ((bf4*)out)[i] = o;
}

// in: batch x K x N (f32, row-major) -> out: batch x N x K (bf16)
__global__ __launch_bounds__(256) void transpose_cvt(
    const float* __restrict__ in, __hip_bfloat16* __restrict__ out, int K, int N)
{
    __shared__ float t[32][33];
    const int bz = blockIdx.z;
    const float* inB = in + (size_t)bz * K * N;
    __hip_bfloat16* outB = out + (size_t)bz * K * N;
    const int n0 = blockIdx.x * 32, k0 = blockIdx.y * 32;
    const int tx = threadIdx.x & 31, ty = threadIdx.x >> 5;  // 32 x 8
    #pragma unroll
    for (int i = 0; i < 32; i += 8)
        t[ty + i][tx] = inB[(size_t)(k0 + ty + i) * N + n0 + tx];
    __syncthreads();
    #pragma unroll
    for (int i = 0; i < 32; i += 8)
        outB[(size_t)(n0 + ty + i) * K + k0 + tx] = __float2bfloat16(t[tx][ty + i]);
}

// f_W2 [NW][HH][NL] f32 -> W2t_all [NW][16][HH] bf16, rows 13..15 zero
__global__ __launch_bounds__(256) void w2t_cvt(
    const float* __restrict__ f_W2, __hip_bfloat16* __restrict__ W2t)
{
    int idx = blockIdx.x * 256 + threadIdx.x;
    if (idx >= NW * 16 * HH) return;
    const int m = idx >> 14;           // /(16*1024)
    const int n = (idx >> 10) & 15;
    const int h = idx & 1023;
    const float v = (n < NL) ? f_W2[((size_t)m * HH + h) * NL + n] : 0.f;
    W2t[idx] = __float2bfloat16(v);
}

// ---------------------------------------------------------------------------
// Chord step (f32, float4-vectorized): 4 rows per block, 64 lanes per row
// ---------------------------------------------------------------------------
__global__ __launch_bounds__(256) void chord_step(
    const float* __restrict__ Vin,   // MM x EE
    const float* __restrict__ Wall,  // MM x NW x 16
    const int* __restrict__ cols,    // NN x NL
    float* __restrict__ Vout,        // MM x EE
    int m)
{
    const int t = threadIdx.x;
    const int r = blockIdx.x * 4 + (t >> 6);
    const int e = t & 63;
    const int b = r >> 12;
    const int n = r & (NN - 1);

    const float* wrow = Wall + ((size_t)r * NW + m) * 16;
    const int* crow = cols + (size_t)n * NL;
    const float4* v4 = (const float4*)Vin;

    float4 acc = v4[(size_t)r * 64 + e];
    #pragma unroll
    for (int l = 0; l < NL; ++l) {
        const int cn = crow[l];
        const float wv = wrow[l];
        const float4 x = v4[((size_t)((b << 12) | cn)) * 64 + e];
        acc.x += wv * x.x; acc.y += wv * x.y;
        acc.z += wv * x.z; acc.w += wv * x.w;
    }
    ((float4*)Vout)[(size_t)r * 64 + e] = acc;
}

// ---------------------------------------------------------------------------
extern "C" void kernel_launch(void* const* d_in, const int* in_sizes, int n_in,
                              void* d_out, int out_size, void* d_ws, size_t ws_size,
                              hipStream_t stream)
{
    const float* V      = (const float*)d_in[0];
    const float* input  = (const float*)d_in[1];
    const float* g_W1   = (const float*)d_in[2];
    const float* g_b1   = (const float*)d_in[3];
    const float* g_W2   = (const float*)d_in[4];
    const float* g_b2   = (const float*)d_in[5];
    const float* f_W1   = (const float*)d_in[6];
    const float* f_b1   = (const float*)d_in[7];
    const float* f_W2   = (const float*)d_in[8];
    const float* f_b2   = (const float*)d_in[9];
    const int*   cols   = (const int*)d_in[10];
    float* out = (float*)d_out;

    char* ws = (char*)d_ws;
    size_t o = 0;
    __hip_bfloat16* Vb     = (__hip_bfloat16*)(ws + o); o += (size_t)MM * EE * 2;        // 8 MB
    __hip_bfloat16* Xb     = (__hip_bfloat16*)(ws + o); o += (size_t)MM * EE * 2;        // 8 MB
    __hip_bfloat16* gW1t   = (__hip_bfloat16*)(ws + o); o += (size_t)HH * EE * 2;        // 512 KB
    __hip_bfloat16* gW2t   = (__hip_bfloat16*)(ws + o); o += (size_t)EE * HH * 2;        // 512 KB
    __hip_bfloat16* fW1t   = (__hip_bfloat16*)(ws + o); o += (size_t)NW * HH * EE * 2;   // 6 MB
    __hip_bfloat16* W2tA   = (__hip_bfloat16*)(ws + o); o += (size_t)NW * 16 * HH * 2;   // 384 KB
    __hip_bfloat16* Whb    = (__hip_bfloat16*)(ws + o); o += (size_t)MM * HH * 2;        // 32 MB (gate only)
    float*          Wall   = (float*)(ws + o);          o += (size_t)MM * NW * 16 * 4;   // 12 MB
    float*          Vbuf   = (float*)(ws + o);          o += (size_t)MM * EE * 4;        // 16 MB

    dim3 blk(256);

    // 0. dtype conversion / weight transposes
    cvt_bf16<<<(MM * EE / 4 + 255) / 256, blk, 0, stream>>>(V, Vb, MM * EE / 4);
    cvt_bf16<<<(MM * EE / 4 + 255) / 256, blk, 0, stream>>>(input, Xb, MM * EE / 4);
    transpose_cvt<<<dim3(HH / 32, EE / 32, 1),  blk, 0, stream>>>(g_W1, gW1t, EE, HH);
    transpose_cvt<<<dim3(EE / 32, HH / 32, 1),  blk, 0, stream>>>(g_W2, gW2t, HH, EE);
    transpose_cvt<<<dim3(HH / 32, EE / 32, NW), blk, 0, stream>>>(f_W1, fW1t, EE, HH);
    w2t_cvt<<<(NW * 16 * HH + 255) / 256, blk, 0, stream>>>(f_W2, W2tA);

    // 1-2. Gate MLP on V
    gemm_bf16<__hip_bfloat16, true><<<dim3(HH / 128, MM / 128), blk, 0, stream>>>(
        Vb, gW1t, g_b1, Whb, MM, HH, EE);
    gemm_bf16<float, false><<<dim3(EE / 128, MM / 128), blk, 0, stream>>>(
        Whb, gW2t, g_b2, out, MM, EE, HH);

    // 3. All 12 levels' link weights in ONE fused launch (no Wh round-trip)
    f_fused<<<dim3(MM / 128, NW), blk, 0, stream>>>(Xb, fW1t, f_b1, W2tA, f_b2, Wall);

    // 4. 12 sequential chord steps, ping-pong out <-> Vbuf (even count -> ends in out)
    const float* cur = out;
    float* nxt = Vbuf;
    for (int m = 0; m < NW; ++m) {
        chord_step<<<MM / 4, blk, 0, stream>>>(cur, Wall, cols, nxt, m);
        float* tswap = (float*)cur;
        cur = nxt;
        nxt = tswap;
    }
}

// Round 7
// 374.287 us; speedup vs baseline: 12.0028x; 1.0828x over previous
//
#include <hip/hip_runtime.h>
#include <hip/hip_bf16.h>
#include <math.h>

// Problem constants
#define BB 4
#define NN 4096
#define EE 256
#define HH 1024
#define NW 12
#define NL 13
#define MM (BB * NN)   // 16384 rows

typedef __attribute__((ext_vector_type(8))) short short8;   // 8 bf16 (4 VGPRs)
typedef __attribute__((ext_vector_type(4))) float f32x4;

// Fast gelu, exp2 form: x * sigmoid(1.5957691*(x + 0.044715 x^3)).
// v_exp_f32 computes 2^x natively; constant pre-folded: 1.5957691*log2(e) = 2.3021193.
__device__ __forceinline__ float gelu_fast(float x) {
    float t = __builtin_fmaf(0.044715f, x * x, 1.0f);
    float e = __builtin_amdgcn_exp2f(-2.3021193f * (x * t));
    return x * __builtin_amdgcn_rcpf(1.0f + e);
}

// Arithmetic bf16 pack, round-half-up (bias only at exact .5 ties): ~4 VALU ops.
__device__ __forceinline__ unsigned pack_bf16_rh(float a, float b) {
    unsigned ua = (__builtin_bit_cast(unsigned, a) + 0x8000u) >> 16;
    unsigned ub = (__builtin_bit_cast(unsigned, b) + 0x8000u) & 0xFFFF0000u;
    return ua | ub;
}

__device__ __forceinline__ void unpack2(unsigned u, float& lo, float& hi) {
    lo = __builtin_bit_cast(float, u << 16);
    hi = __builtin_bit_cast(float, u & 0xFFFF0000u);
}

__device__ __forceinline__ void load_lds16(const void* g, void* l) {
    __builtin_amdgcn_global_load_lds(
        (const __attribute__((address_space(1))) void*)g,
        (__attribute__((address_space(3))) void*)l, 16, 0, 0);
}

// ---------------------------------------------------------------------------
// bf16 MFMA GEMM (m97 structure): C[M,N] = op(A[M,K] @ Bt[N,K]^T + bias)
// 128x128 tile, BK=32, 256 threads (4 waves, 2x2). Used for the gate MLP.
// ---------------------------------------------------------------------------
template<typename OutT, bool GELU>
__global__ __launch_bounds__(256) void gemm_bf16(
    const __hip_bfloat16* __restrict__ A,   // M x K  row-major
    const __hip_bfloat16* __restrict__ Bt,  // N x K  row-major (pre-transposed)
    const float* __restrict__ bias,         // N
    OutT* __restrict__ C,                   // M x N
    int M, int N, int K)
{
    __shared__ __hip_bfloat16 As[128 * 32];
    __shared__ __hip_bfloat16 Bs[128 * 32];

    const int tid = threadIdx.x;
    const int w = tid >> 6, l = tid & 63;
    const int wr = w >> 1, wc = w & 1;       // 2x2 wave grid, each 64x64
    const int row0 = blockIdx.y * 128;
    const int col0 = blockIdx.x * 128;

    const int c0 = w * 64 + l;
    const int c1 = c0 + 256;
    const __hip_bfloat16* gA0 = A  + (size_t)(row0 + (c0 >> 2)) * K + (c0 & 3) * 8;
    const __hip_bfloat16* gA1 = A  + (size_t)(row0 + (c1 >> 2)) * K + (c1 & 3) * 8;
    const __hip_bfloat16* gB0 = Bt + (size_t)(col0 + (c0 >> 2)) * K + (c0 & 3) * 8;
    const __hip_bfloat16* gB1 = Bt + (size_t)(col0 + (c1 >> 2)) * K + (c1 & 3) * 8;
    char* dA0 = (char*)As + w * 1024;
    char* dA1 = (char*)As + w * 1024 + 4096;
    char* dB0 = (char*)Bs + w * 1024;
    char* dB1 = (char*)Bs + w * 1024 + 4096;

    const int lr = l & 15;
    const int lk = (l >> 4) * 8;

    f32x4 acc[4][4] = {};

    for (int k0 = 0; k0 < K; k0 += 32) {
        load_lds16(gA0 + k0, dA0);
        load_lds16(gA1 + k0, dA1);
        load_lds16(gB0 + k0, dB0);
        load_lds16(gB1 + k0, dB1);
        __syncthreads();

        short8 a[4], b[4];
        #pragma unroll
        for (int m = 0; m < 4; ++m)
            a[m] = *(const short8*)&As[(wr * 64 + m * 16 + lr) * 32 + lk];
        #pragma unroll
        for (int n = 0; n < 4; ++n)
            b[n] = *(const short8*)&Bs[(wc * 64 + n * 16 + lr) * 32 + lk];
        #pragma unroll
        for (int m = 0; m < 4; ++m)
            #pragma unroll
            for (int n = 0; n < 4; ++n)
                acc[m][n] = __builtin_amdgcn_mfma_f32_16x16x32_bf16(a[m], b[n], acc[m][n], 0, 0, 0);
        __syncthreads();
    }

    #pragma unroll
    for (int m = 0; m < 4; ++m) {
        #pragma unroll
        for (int n = 0; n < 4; ++n) {
            const int col = col0 + wc * 64 + n * 16 + lr;
            const float bv = bias[col];
            #pragma unroll
            for (int j = 0; j < 4; ++j) {
                const int row = row0 + wr * 64 + m * 16 + (l >> 4) * 4 + j;
                float v = acc[m][n][j] + bv;
                if (GELU) v = gelu_fast(v);
                if constexpr (sizeof(OutT) == 2)
                    C[(size_t)row * N + col] = __float2bfloat16(v);
                else
                    C[(size_t)row * N + col] = v;
            }
        }
    }
}

// ---------------------------------------------------------------------------
// Fused f-level kernel v3 (see round-4 notes):
//  - X fragments in registers, full-K W1 staging per 64-h tile,
//  - T14 async-stage split, wave-private swizzled G half-tile.
// ---------------------------------------------------------------------------
__global__ __launch_bounds__(256, 3) void f_fused(
    const __hip_bfloat16* __restrict__ X,     // MM x EE
    const __hip_bfloat16* __restrict__ W1t,   // NW x HH x EE (pre-transposed)
    const float* __restrict__ b1,             // NW x HH
    const __hip_bfloat16* __restrict__ W2t,   // NW x 16 x HH (padded, transposed)
    const float* __restrict__ b2,             // NW x NL
    float* __restrict__ Wall)                 // MM x NW x 16
{
    __shared__ __hip_bfloat16 Bs[8 * 64 * 32];        // 32 KB: [kk][row][32 elems]
    __shared__ __align__(16) char Gb[4][4096];        // per-wave G [32 r][64 h] (16 KB)
    __shared__ float biasS[HH];                       // 4 KB

    const int tid = threadIdx.x;
    const int w = tid >> 6, l = tid & 63;
    const int row0 = blockIdx.x * 128;
    const int m_lv = blockIdx.y;
    const int lr = l & 15;
    const int g  = l >> 4;
    const int lk = g * 8;

    const __hip_bfloat16* W1m = W1t + (size_t)m_lv * HH * EE;

    // stage bias1 to LDS (256 threads x float4 = 1024 f32)
    ((float4*)biasS)[tid] = ((const float4*)(b1 + (size_t)m_lv * HH))[tid];

    // X fragments in registers: rows w*32 + {0,16} + lr, all 8 k-slices.
    short8 xf[2][8];
    {
        const __hip_bfloat16* xp0 = X + (size_t)(row0 + w * 32 + lr) * EE + lk;
        #pragma unroll
        for (int kk = 0; kk < 8; ++kk) {
            xf[0][kk] = *(const short8*)(xp0 + kk * 32);
            xf[1][kk] = *(const short8*)(xp0 + 16 * EE + kk * 32);
        }
    }

    const __hip_bfloat16* w2p = W2t + ((size_t)m_lv * 16 + lr) * HH + lk;
    char* Gw = Gb[w];

    f32x4 wacc0 = {}, wacc1 = {};

    // prologue: stage ct = 0
    #pragma unroll
    for (int rstep = 0; rstep < 8; ++rstep) {
        const int c = rstep * 256 + tid;
        load_lds16(W1m + (size_t)((c >> 2) & 63) * EE + (c >> 8) * 32 + (c & 3) * 8,
                   (char*)Bs + c * 16);
    }
    __syncthreads();

    #pragma unroll 1
    for (int ct = 0; ct < 16; ++ct) {
        // ---- k-loop: 8 slices x (4 ds_read + 8 MFMA), X from registers ----
        f32x4 acc[4][2] = {};
        #pragma unroll
        for (int kk = 0; kk < 8; ++kk) {
            short8 a[4];
            #pragma unroll
            for (int ni = 0; ni < 4; ++ni)
                a[ni] = *(const short8*)((const char*)Bs +
                         (kk * 4096 + ni * 1024 + lr * 64 + g * 16));
            #pragma unroll
            for (int ni = 0; ni < 4; ++ni) {
                acc[ni][0] = __builtin_amdgcn_mfma_f32_16x16x32_bf16(a[ni], xf[0][kk], acc[ni][0], 0, 0, 0);
                acc[ni][1] = __builtin_amdgcn_mfma_f32_16x16x32_bf16(a[ni], xf[1][kk], acc[ni][1], 0, 0, 0);
            }
        }
        __syncthreads();                       // all waves done reading Bs

        // ---- issue next ct's staging; its flight hides under gelu+mini ----
        if (ct < 15) {
            const __hip_bfloat16* W1n = W1m + (size_t)(ct + 1) * 64 * EE;
            #pragma unroll
            for (int rstep = 0; rstep < 8; ++rstep) {
                const int c = rstep * 256 + tid;
                load_lds16(W1n + (size_t)((c >> 2) & 63) * EE + (c >> 8) * 32 + (c & 3) * 8,
                           (char*)Bs + c * 16);
            }
        }

        // ---- gelu + bias -> bf16 pack -> wave-private swizzled G ----
        #pragma unroll
        for (int ni = 0; ni < 4; ++ni) {
            const float4 bv = *(const float4*)&biasS[ct * 64 + ni * 16 + g * 4];
            #pragma unroll
            for (int mi = 0; mi < 2; ++mi) {
                const int rloc = mi * 16 + lr;
                const float v0 = gelu_fast(acc[ni][mi][0] + bv.x);
                const float v1 = gelu_fast(acc[ni][mi][1] + bv.y);
                const float v2 = gelu_fast(acc[ni][mi][2] + bv.z);
                const float v3 = gelu_fast(acc[ni][mi][3] + bv.w);
                uint2 pk;
                pk.x = pack_bf16_rh(v0, v1);
                pk.y = pack_bf16_rh(v2, v3);
                const int byte = (rloc * 128 + (ni * 16 + g * 4) * 2) ^ ((rloc & 7) << 4);
                *(uint2*)(Gw + byte) = pk;
            }
        }

        // ---- mini-GEMM: Wall-frag += W2t[ct k-range] x G ----
        #pragma unroll
        for (int ks2 = 0; ks2 < 2; ++ks2) {
            const short8 aw = *(const short8*)(w2p + ct * 64 + ks2 * 32);
            {
                const int byte = (lr * 128 + (ks2 * 32 + lk) * 2) ^ ((lr & 7) << 4);
                const short8 bg = *(const short8*)(Gw + byte);
                wacc0 = __builtin_amdgcn_mfma_f32_16x16x32_bf16(aw, bg, wacc0, 0, 0, 0);
            }
            {
                const int rloc = 16 + lr;
                const int byte = (rloc * 128 + (ks2 * 32 + lk) * 2) ^ ((rloc & 7) << 4);
                const short8 bg = *(const short8*)(Gw + byte);
                wacc1 = __builtin_amdgcn_mfma_f32_16x16x32_bf16(aw, bg, wacc1, 0, 0, 0);
            }
        }
        __syncthreads();                       // drain staging; Bs ready for ct+1
    }

    // write Wall: D col = lane&15 (= r-local), row = (lane>>4)*4+j (= link l)
    const float* b2m = b2 + m_lv * NL;
    #pragma unroll
    for (int j = 0; j < 4; ++j) {
        const int lval = g * 4 + j;
        const float bv = (lval < NL) ? b2m[lval] : 0.f;
        {
            const int r = row0 + w * 32 + lr;
            Wall[((size_t)r * NW + m_lv) * 16 + lval] = wacc0[j] + bv;
        }
        {
            const int r = row0 + w * 32 + 16 + lr;
            Wall[((size_t)r * NW + m_lv) * 16 + lval] = wacc1[j] + bv;
        }
    }
}

// ---------------------------------------------------------------------------
// Converters
// ---------------------------------------------------------------------------
struct bf4 { __hip_bfloat16 a, b, c, d; };

__global__ __launch_bounds__(256) void cvt_bf16(
    const float* __restrict__ in, __hip_bfloat16* __restrict__ out, int n4)
{
    int i = blockIdx.x * 256 + threadIdx.x;
    if (i >= n4) return;
    float4 v = ((const float4*)in)[i];
    bf4 o;
    o.a = __float2bfloat16(v.x); o.b = __float2bfloat16(v.y);
    o.c = __float2bfloat16(v.z); o.d = __float2bfloat16(v.w);
    ((bf4*)out)[i] = o;
}

// in: batch x K x N (f32, row-major) -> out: batch x N x K (bf16)
__global__ __launch_bounds__(256) void transpose_cvt(
    const float* __restrict__ in, __hip_bfloat16* __restrict__ out, int K, int N)
{
    __shared__ float t[32][33];
    const int bz = blockIdx.z;
    const float* inB = in + (size_t)bz * K * N;
    __hip_bfloat16* outB = out + (size_t)bz * K * N;
    const int n0 = blockIdx.x * 32, k0 = blockIdx.y * 32;
    const int tx = threadIdx.x & 31, ty = threadIdx.x >> 5;  // 32 x 8
    #pragma unroll
    for (int i = 0; i < 32; i += 8)
        t[ty + i][tx] = inB[(size_t)(k0 + ty + i) * N + n0 + tx];
    __syncthreads();
    #pragma unroll
    for (int i = 0; i < 32; i += 8)
        outB[(size_t)(n0 + ty + i) * K + k0 + tx] = __float2bfloat16(t[tx][ty + i]);
}

// f_W2 [NW][HH][NL] f32 -> W2t_all [NW][16][HH] bf16, rows 13..15 zero
__global__ __launch_bounds__(256) void w2t_cvt(
    const float* __restrict__ f_W2, __hip_bfloat16* __restrict__ W2t)
{
    int idx = blockIdx.x * 256 + threadIdx.x;
    if (idx >= NW * 16 * HH) return;
    const int m = idx >> 14;           // /(16*1024)
    const int n = (idx >> 10) & 15;
    const int h = idx & 1023;
    const float v = (n < NL) ? f_W2[((size_t)m * HH + h) * NL + n] : 0.f;
    W2t[idx] = __float2bfloat16(v);
}

// ---------------------------------------------------------------------------
// Chord step, bf16 state with f32 accumulation. 4 rows/block, 64 lanes/row,
// 4 elems (8 B) per lane. LAST step widens to f32 into d_out.
// ---------------------------------------------------------------------------
template<bool LAST>
__global__ __launch_bounds__(256) void chord_bf16(
    const uint2* __restrict__ Vin,   // MM x 64 (4 bf16 per lane-slot)
    const float* __restrict__ Wall,  // MM x NW x 16
    const int* __restrict__ cols,    // NN x NL
    void* __restrict__ Vout,         // bf16 (MM x 64 uint2) or f32 (MM x 64 float4)
    int m)
{
    const int t = threadIdx.x;
    const int r = blockIdx.x * 4 + (t >> 6);
    const int e = t & 63;
    const int b = r >> 12;
    const int n = r & (NN - 1);

    const float* wrow = Wall + ((size_t)r * NW + m) * 16;
    const int* crow = cols + (size_t)n * NL;

    uint2 s = Vin[(size_t)r * 64 + e];
    float a0, a1, a2, a3;
    unpack2(s.x, a0, a1);
    unpack2(s.y, a2, a3);

    #pragma unroll
    for (int l = 0; l < NL; ++l) {
        const int cn = crow[l];
        const float wv = wrow[l];
        const uint2 x = Vin[((size_t)((b << 12) | cn)) * 64 + e];
        float x0, x1, x2, x3;
        unpack2(x.x, x0, x1);
        unpack2(x.y, x2, x3);
        a0 = __builtin_fmaf(wv, x0, a0);
        a1 = __builtin_fmaf(wv, x1, a1);
        a2 = __builtin_fmaf(wv, x2, a2);
        a3 = __builtin_fmaf(wv, x3, a3);
    }

    if constexpr (LAST) {
        float4 o = {a0, a1, a2, a3};
        ((float4*)Vout)[(size_t)r * 64 + e] = o;
    } else {
        uint2 o;
        o.x = pack_bf16_rh(a0, a1);
        o.y = pack_bf16_rh(a2, a3);
        ((uint2*)Vout)[(size_t)r * 64 + e] = o;
    }
}

// ---------------------------------------------------------------------------
extern "C" void kernel_launch(void* const* d_in, const int* in_sizes, int n_in,
                              void* d_out, int out_size, void* d_ws, size_t ws_size,
                              hipStream_t stream)
{
    const float* V      = (const float*)d_in[0];
    const float* input  = (const float*)d_in[1];
    const float* g_W1   = (const float*)d_in[2];
    const float* g_b1   = (const float*)d_in[3];
    const float* g_W2   = (const float*)d_in[4];
    const float* g_b2   = (const float*)d_in[5];
    const float* f_W1   = (const float*)d_in[6];
    const float* f_b1   = (const float*)d_in[7];
    const float* f_W2   = (const float*)d_in[8];
    const float* f_b2   = (const float*)d_in[9];
    const int*   cols   = (const int*)d_in[10];
    float* out = (float*)d_out;

    char* ws = (char*)d_ws;
    size_t o = 0;
    __hip_bfloat16* Vb     = (__hip_bfloat16*)(ws + o); o += (size_t)MM * EE * 2;        // 8 MB
    __hip_bfloat16* Xb     = (__hip_bfloat16*)(ws + o); o += (size_t)MM * EE * 2;        // 8 MB
    __hip_bfloat16* gW1t   = (__hip_bfloat16*)(ws + o); o += (size_t)HH * EE * 2;        // 512 KB
    __hip_bfloat16* gW2t   = (__hip_bfloat16*)(ws + o); o += (size_t)EE * HH * 2;        // 512 KB
    __hip_bfloat16* fW1t   = (__hip_bfloat16*)(ws + o); o += (size_t)NW * HH * EE * 2;   // 6 MB
    __hip_bfloat16* W2tA   = (__hip_bfloat16*)(ws + o); o += (size_t)NW * 16 * HH * 2;   // 384 KB
    __hip_bfloat16* Whb    = (__hip_bfloat16*)(ws + o); o += (size_t)MM * HH * 2;        // 32 MB (gate only)
    float*          Wall   = (float*)(ws + o);          o += (size_t)MM * NW * 16 * 4;   // 12 MB
    __hip_bfloat16* Vg0    = (__hip_bfloat16*)(ws + o); o += (size_t)MM * EE * 2;        // 8 MB
    __hip_bfloat16* Vg1    = (__hip_bfloat16*)(ws + o); o += (size_t)MM * EE * 2;        // 8 MB

    dim3 blk(256);

    // 0. dtype conversion / weight transposes
    cvt_bf16<<<(MM * EE / 4 + 255) / 256, blk, 0, stream>>>(V, Vb, MM * EE / 4);
    cvt_bf16<<<(MM * EE / 4 + 255) / 256, blk, 0, stream>>>(input, Xb, MM * EE / 4);
    transpose_cvt<<<dim3(HH / 32, EE / 32, 1),  blk, 0, stream>>>(g_W1, gW1t, EE, HH);
    transpose_cvt<<<dim3(EE / 32, HH / 32, 1),  blk, 0, stream>>>(g_W2, gW2t, HH, EE);
    transpose_cvt<<<dim3(HH / 32, EE / 32, NW), blk, 0, stream>>>(f_W1, fW1t, EE, HH);
    w2t_cvt<<<(NW * 16 * HH + 255) / 256, blk, 0, stream>>>(f_W2, W2tA);

    // 1-2. Gate MLP on V (V0 state emitted as bf16)
    gemm_bf16<__hip_bfloat16, true><<<dim3(HH / 128, MM / 128), blk, 0, stream>>>(
        Vb, gW1t, g_b1, Whb, MM, HH, EE);
    gemm_bf16<__hip_bfloat16, false><<<dim3(EE / 128, MM / 128), blk, 0, stream>>>(
        Whb, gW2t, g_b2, Vg0, MM, EE, HH);

    // 3. All 12 levels' link weights in ONE fused launch (no Wh round-trip)
    f_fused<<<dim3(MM / 128, NW), blk, 0, stream>>>(Xb, fW1t, f_b1, W2tA, f_b2, Wall);

    // 4. 12 sequential chord steps on bf16 state; final step widens to f32 out
    const __hip_bfloat16* cur = Vg0;
    __hip_bfloat16* nxt = Vg1;
    for (int m = 0; m < NW - 1; ++m) {
        chord_bf16<false><<<MM / 4, blk, 0, stream>>>(
            (const uint2*)cur, Wall, cols, nxt, m);
        __hip_bfloat16* tswap = (__hip_bfloat16*)cur;
        cur = nxt;
        nxt = tswap;
    }
    chord_bf16<true><<<MM / 4, blk, 0, stream>>>(
        (const uint2*)cur, Wall, cols, out, NW - 1);
}